// Round 1
// baseline (688.106 us; speedup 1.0000x reference)
//
#include <hip/hip_runtime.h>
#include <math.h>

#define B_ 1024
#define S_ 128
#define H_ 1024
#define E_ 16
#define HID_ 1024
#define K_ 4
#define C_ 3
#define EPS_ 1e-5f

// ---------------------------------------------------------------------------
// K1: m = mean_s(hidden), cls = hidden[:,0,:]. One block per sample row (256
// threads x float4 = 1024 cols). 512 MB streamed -> memory-bound floor.
// ---------------------------------------------------------------------------
__global__ __launch_bounds__(256) void mean_cls_kernel(const float* __restrict__ hs,
                                                       float* __restrict__ mout,
                                                       float* __restrict__ cls) {
  int gid = blockIdx.x * 256 + threadIdx.x;
  int b = gid >> 8;                 // H/4 = 256 float4 per row
  int h4 = (gid & 255) << 2;
  const float* p = hs + (size_t)b * S_ * H_ + h4;
  float4 v0 = *(const float4*)p;    // s = 0
  *(float4*)(cls + (size_t)b * H_ + h4) = v0;
  float sx = v0.x, sy = v0.y, sz = v0.z, sw = v0.w;
#pragma unroll 4
  for (int s = 1; s < S_; ++s) {
    float4 v = *(const float4*)(p + (size_t)s * H_);
    sx += v.x; sy += v.y; sz += v.z; sw += v.w;
  }
  const float inv = 1.0f / (float)S_;
  float4 r; r.x = sx * inv; r.y = sy * inv; r.z = sz * inv; r.w = sw * inv;
  *(float4*)(mout + (size_t)b * H_ + h4) = r;
}

// ---------------------------------------------------------------------------
// K2: router logits (cls @ Wr + br), top-4 (tie -> lower index, like
// lax.top_k), softmax over top-4, and per-expert pair lists via atomics.
// One wave per sample.
// ---------------------------------------------------------------------------
__global__ void router_kernel(const float* __restrict__ hs, const float* __restrict__ Wr,
                              const float* __restrict__ br,
                              int* __restrict__ topk_idx, float* __restrict__ topk_prob,
                              int* __restrict__ counts, int* __restrict__ pairlist) {
  int b = blockIdx.x;
  int lane = threadIdx.x;           // 64
  const float* cls = hs + (size_t)b * S_ * H_;
  int e = lane & 15, part = lane >> 4;
  float sum = 0.0f;
  for (int i = part * 256; i < part * 256 + 256; ++i)
    sum = fmaf(cls[i], Wr[i * E_ + e], sum);
  sum += __shfl_down(sum, 32);
  sum += __shfl_down(sum, 16);
  __shared__ float logits[E_];
  if (lane < E_) logits[lane] = sum + br[lane];
  __syncthreads();
  if (lane == 0) {
    float vals[E_];
    for (int i = 0; i < E_; ++i) vals[i] = logits[i];
    int idx[K_]; float tv[K_];
    for (int k = 0; k < K_; ++k) {
      int bi = 0; float bv = -1e30f;
      for (int i = 0; i < E_; ++i) { if (vals[i] > bv) { bv = vals[i]; bi = i; } }
      idx[k] = bi; tv[k] = bv; vals[bi] = -1e30f;
    }
    float mx = tv[0], ssum = 0.0f, p[K_];
    for (int k = 0; k < K_; ++k) { p[k] = expf(tv[k] - mx); ssum += p[k]; }
    for (int k = 0; k < K_; ++k) {
      p[k] /= ssum;
      topk_idx[b * K_ + k] = idx[k];
      topk_prob[b * K_ + k] = p[k];
      int pos = atomicAdd(&counts[idx[k]], 1);
      pairlist[idx[k] * B_ + pos] = b * K_ + k;   // pair code = b*4+k
    }
  }
}

// ---------------------------------------------------------------------------
// K3: t = tanh(cls @ Wd + bd). 128x128 tile, BK=16, 256 thr, 8x8 microtile.
// a-frags read as float4 (broadcast-friendly, As transposed+padded); b-frags
// read strided (col = tx + 16*j) -> conflict-free scalar LDS reads.
// ---------------------------------------------------------------------------
__global__ __launch_bounds__(256) void gemm_tanh_kernel(const float* __restrict__ A,
                                                        const float* __restrict__ Bw,
                                                        const float* __restrict__ bias,
                                                        float* __restrict__ Cm) {
  __shared__ float As[16][132];
  __shared__ float Bs[16][128];
  const int tid = threadIdx.x;
  const int tx = tid & 15, ty = tid >> 4;
  const int m0 = blockIdx.y * 128, n0 = blockIdx.x * 128;
  const int ar = tid >> 2, ac4 = (tid & 3) << 2;
  const int br2 = tid >> 5, bc4 = (tid & 31) << 2;
  float acc[8][8] = {};
  for (int k0 = 0; k0 < H_; k0 += 16) {
    float4 a0 = *(const float4*)&A[(size_t)(m0 + ar) * H_ + k0 + ac4];
    float4 a1 = *(const float4*)&A[(size_t)(m0 + ar + 64) * H_ + k0 + ac4];
    float4 b0 = *(const float4*)&Bw[(size_t)(k0 + br2) * H_ + n0 + bc4];
    float4 b1 = *(const float4*)&Bw[(size_t)(k0 + br2 + 8) * H_ + n0 + bc4];
    As[ac4 + 0][ar] = a0.x; As[ac4 + 1][ar] = a0.y; As[ac4 + 2][ar] = a0.z; As[ac4 + 3][ar] = a0.w;
    As[ac4 + 0][ar + 64] = a1.x; As[ac4 + 1][ar + 64] = a1.y; As[ac4 + 2][ar + 64] = a1.z; As[ac4 + 3][ar + 64] = a1.w;
    *(float4*)&Bs[br2][bc4] = b0;
    *(float4*)&Bs[br2 + 8][bc4] = b1;
    __syncthreads();
#pragma unroll
    for (int kk = 0; kk < 16; ++kk) {
      float4 af0 = *(const float4*)&As[kk][ty * 8];
      float4 af1 = *(const float4*)&As[kk][ty * 8 + 4];
      float af[8] = {af0.x, af0.y, af0.z, af0.w, af1.x, af1.y, af1.z, af1.w};
      float bf[8];
#pragma unroll
      for (int j = 0; j < 8; ++j) bf[j] = Bs[kk][tx + 16 * j];
#pragma unroll
      for (int i = 0; i < 8; ++i)
#pragma unroll
        for (int j = 0; j < 8; ++j)
          acc[i][j] = fmaf(af[i], bf[j], acc[i][j]);
    }
    __syncthreads();
  }
#pragma unroll
  for (int i = 0; i < 8; ++i) {
    int row = m0 + ty * 8 + i;
#pragma unroll
    for (int j = 0; j < 8; ++j) {
      int col = n0 + tx + 16 * j;
      Cm[(size_t)row * H_ + col] = tanhf(acc[i][j] + bias[col]);
    }
  }
}

// ---------------------------------------------------------------------------
// K4: original_logits = t @ Wo + bo (1024x3). One wave per sample.
// ---------------------------------------------------------------------------
__global__ void ologits_kernel(const float* __restrict__ t, const float* __restrict__ Wo,
                               const float* __restrict__ bo, float* __restrict__ ol) {
  int b = blockIdx.x; int lane = threadIdx.x;
  const float* tr = t + (size_t)b * H_;
  float s0 = 0, s1 = 0, s2 = 0;
  for (int h = lane; h < H_; h += 64) {
    float v = tr[h];
    s0 = fmaf(v, Wo[h * 3 + 0], s0);
    s1 = fmaf(v, Wo[h * 3 + 1], s1);
    s2 = fmaf(v, Wo[h * 3 + 2], s2);
  }
#pragma unroll
  for (int off = 32; off; off >>= 1) {
    s0 += __shfl_down(s0, off); s1 += __shfl_down(s1, off); s2 += __shfl_down(s2, off);
  }
  if (lane == 0) {
    ol[b * 3 + 0] = s0 + bo[0]; ol[b * 3 + 1] = s1 + bo[1]; ol[b * 3 + 2] = s2 + bo[2];
  }
}

// ---------------------------------------------------------------------------
// K3c: Wcomb[e,d,:] = We2[e,d,:] @ Wp  (collapses the second expert einsum:
// no nonlinearity between We2 and Wp). One wave per (e,d) row, 4 waves/block.
// ---------------------------------------------------------------------------
__global__ __launch_bounds__(256) void wcomb_kernel(const float* __restrict__ We2,
                                                    const float* __restrict__ Wp,
                                                    float* __restrict__ Wcomb) {
  const int row = blockIdx.x * 4 + (threadIdx.x >> 6);  // e*HID + d
  const int lane = threadIdx.x & 63;
  const float* wr = We2 + (size_t)row * HID_;
  float s0 = 0, s1 = 0, s2 = 0;
  for (int f = lane; f < HID_; f += 64) {
    float v = wr[f];
    s0 = fmaf(v, Wp[f * 3 + 0], s0);
    s1 = fmaf(v, Wp[f * 3 + 1], s1);
    s2 = fmaf(v, Wp[f * 3 + 2], s2);
  }
#pragma unroll
  for (int off = 32; off; off >>= 1) {
    s0 += __shfl_down(s0, off); s1 += __shfl_down(s1, off); s2 += __shfl_down(s2, off);
  }
  if (lane == 0) {
    Wcomb[row * 3 + 0] = s0; Wcomb[row * 3 + 1] = s1; Wcomb[row * 3 + 2] = s2;
  }
}

__global__ void bcomb_kernel(const float* __restrict__ be2, const float* __restrict__ Wp,
                             const float* __restrict__ bp, float* __restrict__ bcomb) {
  const int e = blockIdx.x; const int lane = threadIdx.x;
  const float* wr = be2 + (size_t)e * HID_;
  float s0 = 0, s1 = 0, s2 = 0;
  for (int f = lane; f < HID_; f += 64) {
    float v = wr[f];
    s0 = fmaf(v, Wp[f * 3 + 0], s0);
    s1 = fmaf(v, Wp[f * 3 + 1], s1);
    s2 = fmaf(v, Wp[f * 3 + 2], s2);
  }
#pragma unroll
  for (int off = 32; off; off >>= 1) {
    s0 += __shfl_down(s0, off); s1 += __shfl_down(s1, off); s2 += __shfl_down(s2, off);
  }
  if (lane == 0) {
    bcomb[e * 3 + 0] = s0 + bp[0]; bcomb[e * 3 + 1] = s1 + bp[1]; bcomb[e * 3 + 2] = s2 + bp[2];
  }
}

// ---------------------------------------------------------------------------
// K5a: grouped expert GEMM. For expert e with n_e routed pairs:
// h1[pair, :] = m[b_pair, :] @ We1[e] + be1[e]. Same tile scheme as K3.
// Grid (n_tiles=8, m_tiles=8, e=16); blocks beyond n_e exit early.
// ---------------------------------------------------------------------------
__global__ __launch_bounds__(256) void expert_gemm_kernel(const float* __restrict__ Min,
                                                          const float* __restrict__ We1,
                                                          const float* __restrict__ be1,
                                                          const int* __restrict__ counts,
                                                          const int* __restrict__ pairlist,
                                                          float* __restrict__ h1) {
  const int e = blockIdx.z;
  const int n_e = counts[e];
  const int m0 = blockIdx.y * 128;
  if (m0 >= n_e) return;
  const int n0 = blockIdx.x * 128;
  __shared__ float As[16][132];
  __shared__ float Bs[16][128];
  const int tid = threadIdx.x;
  const int tx = tid & 15, ty = tid >> 4;
  const int ar = tid >> 2, ac4 = (tid & 3) << 2;
  const int br2 = tid >> 5, bc4 = (tid & 31) << 2;
  int r0 = m0 + ar;      if (r0 >= n_e) r0 = n_e - 1;
  int r1 = m0 + ar + 64; if (r1 >= n_e) r1 = n_e - 1;
  const float* arow0 = Min + (size_t)(pairlist[e * B_ + r0] >> 2) * H_;
  const float* arow1 = Min + (size_t)(pairlist[e * B_ + r1] >> 2) * H_;
  const float* Bw = We1 + (size_t)e * H_ * HID_;
  float acc[8][8] = {};
  for (int k0 = 0; k0 < H_; k0 += 16) {
    float4 a0 = *(const float4*)&arow0[k0 + ac4];
    float4 a1 = *(const float4*)&arow1[k0 + ac4];
    float4 b0 = *(const float4*)&Bw[(size_t)(k0 + br2) * HID_ + n0 + bc4];
    float4 b1 = *(const float4*)&Bw[(size_t)(k0 + br2 + 8) * HID_ + n0 + bc4];
    As[ac4 + 0][ar] = a0.x; As[ac4 + 1][ar] = a0.y; As[ac4 + 2][ar] = a0.z; As[ac4 + 3][ar] = a0.w;
    As[ac4 + 0][ar + 64] = a1.x; As[ac4 + 1][ar + 64] = a1.y; As[ac4 + 2][ar + 64] = a1.z; As[ac4 + 3][ar + 64] = a1.w;
    *(float4*)&Bs[br2][bc4] = b0;
    *(float4*)&Bs[br2 + 8][bc4] = b1;
    __syncthreads();
#pragma unroll
    for (int kk = 0; kk < 16; ++kk) {
      float4 af0 = *(const float4*)&As[kk][ty * 8];
      float4 af1 = *(const float4*)&As[kk][ty * 8 + 4];
      float af[8] = {af0.x, af0.y, af0.z, af0.w, af1.x, af1.y, af1.z, af1.w};
      float bf[8];
#pragma unroll
      for (int j = 0; j < 8; ++j) bf[j] = Bs[kk][tx + 16 * j];
#pragma unroll
      for (int i = 0; i < 8; ++i)
#pragma unroll
        for (int j = 0; j < 8; ++j)
          acc[i][j] = fmaf(af[i], bf[j], acc[i][j]);
    }
    __syncthreads();
  }
#pragma unroll
  for (int i = 0; i < 8; ++i) {
    int rg = m0 + ty * 8 + i;
    if (rg < n_e) {
      int pair = pairlist[e * B_ + rg];
#pragma unroll
      for (int j = 0; j < 8; ++j) {
        int col = n0 + tx + 16 * j;
        h1[(size_t)pair * HID_ + col] = acc[i][j] + be1[e * HID_ + col];
      }
    }
  }
}

// ---------------------------------------------------------------------------
// K5b: per pair row: LN(h1) with (g1,beta1), exact gelu (erf), then dot with
// Wcomb[e] (3 cols) + bcomb, scaled by routing prob. One block per pair.
// ---------------------------------------------------------------------------
__device__ __forceinline__ float blockSum256(float v, float* red) {
#pragma unroll
  for (int off = 32; off; off >>= 1) v += __shfl_down(v, off);
  const int wid = threadIdx.x >> 6;
  __syncthreads();
  if ((threadIdx.x & 63) == 0) red[wid] = v;
  __syncthreads();
  return red[0] + red[1] + red[2] + red[3];
}

__global__ __launch_bounds__(256) void lngelu_kernel(const float* __restrict__ h1,
                                                     const float* __restrict__ g1,
                                                     const float* __restrict__ beta1,
                                                     const int* __restrict__ topk_idx,
                                                     const float* __restrict__ topk_prob,
                                                     const float* __restrict__ Wcomb,
                                                     const float* __restrict__ bcomb,
                                                     float* __restrict__ contrib) {
  const int pair = blockIdx.x;
  const int e = topk_idx[pair];
  const float prob = topk_prob[pair];
  const int tid = threadIdx.x;
  __shared__ float red[4];
  float4 x = *(const float4*)&h1[(size_t)pair * HID_ + tid * 4];
  float s = x.x + x.y + x.z + x.w;
  s = blockSum256(s, red);
  const float mu = s * (1.0f / HID_);
  float dx = x.x - mu, dy = x.y - mu, dz = x.z - mu, dw = x.w - mu;
  float sq = dx * dx + dy * dy + dz * dz + dw * dw;
  sq = blockSum256(sq, red);
  const float inv = 1.0f / sqrtf(sq * (1.0f / HID_) + EPS_);
  const int d = tid * 4;
  float y[4] = {dx * inv, dy * inv, dz * inv, dw * inv};
  float c0 = 0, c1 = 0, c2 = 0;
#pragma unroll
  for (int i = 0; i < 4; ++i) {
    float g = g1[e * HID_ + d + i], bb = beta1[e * HID_ + d + i];
    float v = y[i] * g + bb;
    v = 0.5f * v * (1.0f + erff(v * 0.70710678118654752440f));  // exact gelu
    const float* wc = &Wcomb[(size_t)(e * HID_ + d + i) * 3];
    c0 = fmaf(v, wc[0], c0); c1 = fmaf(v, wc[1], c1); c2 = fmaf(v, wc[2], c2);
  }
  c0 = blockSum256(c0, red);
  c1 = blockSum256(c1, red);
  c2 = blockSum256(c2, red);
  if (tid == 0) {
    contrib[pair * 3 + 0] = prob * (c0 + bcomb[e * 3 + 0]);
    contrib[pair * 3 + 1] = prob * (c1 + bcomb[e * 3 + 1]);
    contrib[pair * 3 + 2] = prob * (c2 + bcomb[e * 3 + 2]);
  }
}

// ---------------------------------------------------------------------------
// K6: fixed-order k-sum of contribs (deterministic), concat, 6->3 GEMM,
// LN over 3, relu, 3->3 GEMM. One thread per sample.
// ---------------------------------------------------------------------------
__global__ void final_kernel(const float* __restrict__ ol, const float* __restrict__ contrib,
                             const float* __restrict__ Wf1, const float* __restrict__ bf1,
                             const float* __restrict__ gf, const float* __restrict__ betaf,
                             const float* __restrict__ Wf2, const float* __restrict__ bf2,
                             float* __restrict__ out) {
  int b = blockIdx.x * blockDim.x + threadIdx.x;
  if (b >= B_) return;
  float comb[6];
  comb[0] = ol[b * 3 + 0]; comb[1] = ol[b * 3 + 1]; comb[2] = ol[b * 3 + 2];
  float mo0 = 0, mo1 = 0, mo2 = 0;
#pragma unroll
  for (int k = 0; k < K_; ++k) {
    mo0 += contrib[(b * K_ + k) * 3 + 0];
    mo1 += contrib[(b * K_ + k) * 3 + 1];
    mo2 += contrib[(b * K_ + k) * 3 + 2];
  }
  comb[3] = mo0; comb[4] = mo1; comb[5] = mo2;
  float z[3];
#pragma unroll
  for (int c = 0; c < 3; ++c) {
    float s = bf1[c];
#pragma unroll
    for (int i = 0; i < 6; ++i) s = fmaf(comb[i], Wf1[i * 3 + c], s);
    z[c] = s;
  }
  float mu = (z[0] + z[1] + z[2]) * (1.0f / 3.0f);
  float v0 = z[0] - mu, v1 = z[1] - mu, v2 = z[2] - mu;
  float var = (v0 * v0 + v1 * v1 + v2 * v2) * (1.0f / 3.0f);
  float inv = 1.0f / sqrtf(var + EPS_);
  float r[3];
#pragma unroll
  for (int c = 0; c < 3; ++c) {
    float zz = (z[c] - mu) * inv * gf[c] + betaf[c];
    r[c] = zz > 0.0f ? zz : 0.0f;
  }
#pragma unroll
  for (int c = 0; c < 3; ++c) {
    float s = bf2[c];
#pragma unroll
    for (int i = 0; i < 3; ++i) s = fmaf(r[i], Wf2[i * 3 + c], s);
    out[b * 3 + c] = s;
  }
}

// ---------------------------------------------------------------------------
extern "C" void kernel_launch(void* const* d_in, const int* in_sizes, int n_in,
                              void* d_out, int out_size, void* d_ws, size_t ws_size,
                              hipStream_t stream) {
  const float* hs    = (const float*)d_in[0];
  const float* Wd    = (const float*)d_in[1];
  const float* bd    = (const float*)d_in[2];
  const float* Wo    = (const float*)d_in[3];
  const float* bo    = (const float*)d_in[4];
  const float* Wr    = (const float*)d_in[5];
  const float* br    = (const float*)d_in[6];
  const float* We1   = (const float*)d_in[7];
  const float* be1   = (const float*)d_in[8];
  const float* g1    = (const float*)d_in[9];
  const float* beta1 = (const float*)d_in[10];
  const float* We2   = (const float*)d_in[11];
  const float* be2   = (const float*)d_in[12];
  const float* Wp    = (const float*)d_in[13];
  const float* bp    = (const float*)d_in[14];
  const float* Wf1   = (const float*)d_in[15];
  const float* bf1   = (const float*)d_in[16];
  const float* gf    = (const float*)d_in[17];
  const float* betaf = (const float*)d_in[18];
  const float* Wf2   = (const float*)d_in[19];
  const float* bf2   = (const float*)d_in[20];
  float* out = (float*)d_out;

  char* w = (char*)d_ws;
  size_t off = 0;
  auto alloc = [&](size_t n_elts) {
    float* p = (float*)(w + off);
    off += n_elts * 4; off = (off + 255) & ~(size_t)255;
    return p;
  };
  float* ws_m    = alloc((size_t)B_ * H_);
  float* ws_cls  = alloc((size_t)B_ * H_);
  float* ws_t    = alloc((size_t)B_ * H_);
  float* ws_h1   = alloc((size_t)B_ * K_ * HID_);
  float* ws_wc   = alloc((size_t)E_ * HID_ * 3);
  float* ws_bc   = alloc(E_ * 3);
  float* ws_ol   = alloc(B_ * 3);
  float* ws_ctr  = alloc(B_ * K_ * 3);
  float* ws_prob = alloc(B_ * K_);
  int* ws_idx = (int*)alloc(B_ * K_);
  int* ws_cnt = (int*)alloc(E_);
  int* ws_pl  = (int*)alloc(E_ * B_);
  if (off > ws_size) return;  // insufficient workspace (will show as incorrect, not corrupt)

  hipMemsetAsync(ws_cnt, 0, E_ * sizeof(int), stream);

  mean_cls_kernel<<<(B_ * H_ / 4) / 256, 256, 0, stream>>>(hs, ws_m, ws_cls);
  router_kernel<<<B_, 64, 0, stream>>>(hs, Wr, br, ws_idx, ws_prob, ws_cnt, ws_pl);
  gemm_tanh_kernel<<<dim3(8, 8), 256, 0, stream>>>(ws_cls, Wd, bd, ws_t);
  ologits_kernel<<<B_, 64, 0, stream>>>(ws_t, Wo, bo, ws_ol);
  wcomb_kernel<<<E_ * HID_ / 4, 256, 0, stream>>>(We2, Wp, ws_wc);
  bcomb_kernel<<<E_, 64, 0, stream>>>(be2, Wp, bp, ws_bc);
  expert_gemm_kernel<<<dim3(8, 8, E_), 256, 0, stream>>>(ws_m, We1, be1, ws_cnt, ws_pl, ws_h1);
  lngelu_kernel<<<B_ * K_, 256, 0, stream>>>(ws_h1, g1, beta1, ws_idx, ws_prob, ws_wc, ws_bc, ws_ctr);
  final_kernel<<<(B_ + 255) / 256, 256, 0, stream>>>(ws_ol, ws_ctr, Wf1, bf1, gf, betaf, Wf2, bf2, out);
}

// Round 2
// 453.918 us; speedup vs baseline: 1.5159x; 1.5159x over previous
//
#include <hip/hip_runtime.h>
#include <math.h>

#define B_ 1024
#define S_ 128
#define H_ 1024
#define E_ 16
#define HID_ 1024
#define K_ 4
#define C_ 3
#define EPS_ 1e-5f

typedef __attribute__((ext_vector_type(8))) __bf16 bf16x8;
typedef __attribute__((ext_vector_type(4))) float f32x4;

__device__ __forceinline__ ushort bf16_rn(float f) {
  unsigned u = __float_as_uint(f);
  u += 0x7FFF + ((u >> 16) & 1);
  return (ushort)(u >> 16);
}
__device__ __forceinline__ float bf16_to_f(ushort h) {
  return __uint_as_float(((unsigned)h) << 16);
}
__device__ __forceinline__ void split2(float f, ushort& h, ushort& l) {
  h = bf16_rn(f);
  l = bf16_rn(f - bf16_to_f(h));
}
__device__ __forceinline__ void gload_lds16(const void* g, void* l) {
  __builtin_amdgcn_global_load_lds((const __attribute__((address_space(1))) void*)g,
                                   (__attribute__((address_space(3))) void*)l, 16, 0, 0);
}

// ---------------------------------------------------------------------------
// K1: m = mean_s(hidden), cls = hidden[:,0,:]; emit bf16 hi/lo splits of both
// (the only consumers of m/cls-as-GEMM-A are the MFMA GEMMs; router reads hs).
// ---------------------------------------------------------------------------
__global__ __launch_bounds__(256) void mean_cls_kernel(const float* __restrict__ hs,
                                                       ushort* __restrict__ m_hi, ushort* __restrict__ m_lo,
                                                       ushort* __restrict__ cls_hi, ushort* __restrict__ cls_lo) {
  int gid = blockIdx.x * 256 + threadIdx.x;
  int b = gid >> 8;                 // H/4 = 256 float4 per row
  int h4 = (gid & 255) << 2;
  const float* p = hs + (size_t)b * S_ * H_ + h4;
  float4 v0 = *(const float4*)p;    // s = 0
  float sx = v0.x, sy = v0.y, sz = v0.z, sw = v0.w;
#pragma unroll 4
  for (int s = 1; s < S_; ++s) {
    float4 v = *(const float4*)(p + (size_t)s * H_);
    sx += v.x; sy += v.y; sz += v.z; sw += v.w;
  }
  const float inv = 1.0f / (float)S_;
  float mv[4] = {sx * inv, sy * inv, sz * inv, sw * inv};
  float cv[4] = {v0.x, v0.y, v0.z, v0.w};
  ushort4 mh, ml, ch, cl;
  split2(mv[0], mh.x, ml.x); split2(mv[1], mh.y, ml.y); split2(mv[2], mh.z, ml.z); split2(mv[3], mh.w, ml.w);
  split2(cv[0], ch.x, cl.x); split2(cv[1], ch.y, cl.y); split2(cv[2], ch.z, cl.z); split2(cv[3], ch.w, cl.w);
  size_t o = (size_t)b * H_ + h4;
  *(ushort4*)&m_hi[o] = mh; *(ushort4*)&m_lo[o] = ml;
  *(ushort4*)&cls_hi[o] = ch; *(ushort4*)&cls_lo[o] = cl;
}

// ---------------------------------------------------------------------------
// K1b: weight transpose + hi/lo split. in: [1024][1024] f32 per matrix z;
// out: [1024][1024] bf16 (transposed, N-major) hi and lo.
// ---------------------------------------------------------------------------
__global__ __launch_bounds__(256) void wsplit_t_kernel(const float* __restrict__ in,
                                                       ushort* __restrict__ out_hi,
                                                       ushort* __restrict__ out_lo) {
  __shared__ float t[64][65];
  const int k0 = blockIdx.x * 64, n0 = blockIdx.y * 64;
  const size_t mbase = (size_t)blockIdx.z * (1024 * 1024);
  const int tid = threadIdx.x;
  const int c4 = (tid & 15) << 2;
  const int r0 = tid >> 4;
#pragma unroll
  for (int p = 0; p < 4; ++p) {
    int row = r0 + p * 16;
    float4 v = *(const float4*)&in[mbase + (size_t)(k0 + row) * 1024 + n0 + c4];
    t[row][c4] = v.x; t[row][c4 + 1] = v.y; t[row][c4 + 2] = v.z; t[row][c4 + 3] = v.w;
  }
  __syncthreads();
  const int k4 = (tid & 15) << 2;
#pragma unroll
  for (int p = 0; p < 4; ++p) {
    int n = r0 + p * 16;
    ushort4 hh, ll;
    split2(t[k4 + 0][n], hh.x, ll.x);
    split2(t[k4 + 1][n], hh.y, ll.y);
    split2(t[k4 + 2][n], hh.z, ll.z);
    split2(t[k4 + 3][n], hh.w, ll.w);
    size_t o = mbase + (size_t)(n0 + n) * 1024 + k0 + k4;
    *(ushort4*)&out_hi[o] = hh;
    *(ushort4*)&out_lo[o] = ll;
  }
}

// ---------------------------------------------------------------------------
// K2: router (unchanged): logits, top-4, softmax, per-expert pair lists.
// ---------------------------------------------------------------------------
__global__ void router_kernel(const float* __restrict__ hs, const float* __restrict__ Wr,
                              const float* __restrict__ br,
                              int* __restrict__ topk_idx, float* __restrict__ topk_prob,
                              int* __restrict__ counts, int* __restrict__ pairlist) {
  int b = blockIdx.x;
  int lane = threadIdx.x;           // 64
  const float* cls = hs + (size_t)b * S_ * H_;
  int e = lane & 15, part = lane >> 4;
  float sum = 0.0f;
  for (int i = part * 256; i < part * 256 + 256; ++i)
    sum = fmaf(cls[i], Wr[i * E_ + e], sum);
  sum += __shfl_down(sum, 32);
  sum += __shfl_down(sum, 16);
  __shared__ float logits[E_];
  if (lane < E_) logits[lane] = sum + br[lane];
  __syncthreads();
  if (lane == 0) {
    float vals[E_];
    for (int i = 0; i < E_; ++i) vals[i] = logits[i];
    int idx[K_]; float tv[K_];
    for (int k = 0; k < K_; ++k) {
      int bi = 0; float bv = -1e30f;
      for (int i = 0; i < E_; ++i) { if (vals[i] > bv) { bv = vals[i]; bi = i; } }
      idx[k] = bi; tv[k] = bv; vals[bi] = -1e30f;
    }
    float mx = tv[0], ssum = 0.0f, p[K_];
    for (int k = 0; k < K_; ++k) { p[k] = expf(tv[k] - mx); ssum += p[k]; }
    for (int k = 0; k < K_; ++k) {
      p[k] /= ssum;
      topk_idx[b * K_ + k] = idx[k];
      topk_prob[b * K_ + k] = p[k];
      int pos = atomicAdd(&counts[idx[k]], 1);
      pairlist[idx[k] * B_ + pos] = b * K_ + k;   // pair code = b*4+k
    }
  }
}

// ---------------------------------------------------------------------------
// K3: t = tanh(cls @ Wd + bd) via split-bf16 3-MFMA. 128x128 tile, BK=32,
// 4 waves (2x2 of 64x64). LDS is fragment-ordered 16x32 subtiles so that
// global_load_lds (linear lane order) lands exactly in MFMA fragment layout
// and ds_read_b128 frag loads are lane-linear (conflict-free).
// ---------------------------------------------------------------------------
__global__ __launch_bounds__(256) void gemm_tanh_mfma(const ushort* __restrict__ Ahi, const ushort* __restrict__ Alo,
                                                      const ushort* __restrict__ Bhi, const ushort* __restrict__ Blo,
                                                      const float* __restrict__ bias, float* __restrict__ Cm) {
  __shared__ __align__(16) ushort ldsAh[4096], ldsAl[4096], ldsBh[4096], ldsBl[4096];
  const int tid = threadIdx.x;
  const int lane = tid & 63, w = tid >> 6;
  const int m0 = blockIdx.y * 128, n0 = blockIdx.x * 128;
  const ushort* srcp[8];
  ushort* ldst;
  {
    const ushort* sbase;
    if (w < 2) {
      sbase = (w == 0) ? Ahi : Alo;
      ldst = (w == 0) ? ldsAh : ldsAl;
#pragma unroll
      for (int s = 0; s < 8; ++s) {
        int row = m0 + s * 16 + (lane & 15);
        srcp[s] = sbase + (size_t)row * H_ + ((lane >> 4) << 3);
      }
    } else {
      sbase = (w == 2) ? Bhi : Blo;
      ldst = (w == 2) ? ldsBh : ldsBl;
#pragma unroll
      for (int s = 0; s < 8; ++s) {
        int col = n0 + s * 16 + (lane & 15);
        srcp[s] = sbase + (size_t)col * H_ + ((lane >> 4) << 3);
      }
    }
  }
  const int wr = w >> 1, wc = w & 1;
  f32x4 acc[4][4] = {};
  for (int k0 = 0; k0 < H_; k0 += 32) {
#pragma unroll
    for (int s = 0; s < 8; ++s)
      gload_lds16(srcp[s] + k0, ldst + s * 512);
    __syncthreads();
    bf16x8 ah[4], al[4], bh[4], bl[4];
#pragma unroll
    for (int i = 0; i < 4; ++i) {
      int off = (wr * 4 + i) * 512 + lane * 8;
      ah[i] = *(const bf16x8*)&ldsAh[off];
      al[i] = *(const bf16x8*)&ldsAl[off];
    }
#pragma unroll
    for (int j = 0; j < 4; ++j) {
      int off = (wc * 4 + j) * 512 + lane * 8;
      bh[j] = *(const bf16x8*)&ldsBh[off];
      bl[j] = *(const bf16x8*)&ldsBl[off];
    }
#pragma unroll
    for (int i = 0; i < 4; ++i)
#pragma unroll
      for (int j = 0; j < 4; ++j) {
        acc[i][j] = __builtin_amdgcn_mfma_f32_16x16x32_bf16(ah[i], bh[j], acc[i][j], 0, 0, 0);
        acc[i][j] = __builtin_amdgcn_mfma_f32_16x16x32_bf16(ah[i], bl[j], acc[i][j], 0, 0, 0);
        acc[i][j] = __builtin_amdgcn_mfma_f32_16x16x32_bf16(al[i], bh[j], acc[i][j], 0, 0, 0);
      }
    __syncthreads();
  }
  const int lr = (lane >> 4) << 2, lc = lane & 15;
#pragma unroll
  for (int i = 0; i < 4; ++i) {
    int row = m0 + wr * 64 + i * 16 + lr;
#pragma unroll
    for (int j = 0; j < 4; ++j) {
      int col = n0 + wc * 64 + j * 16 + lc;
      float bsv = bias[col];
#pragma unroll
      for (int r = 0; r < 4; ++r)
        Cm[(size_t)(row + r) * H_ + col] = tanhf(acc[i][j][r] + bsv);
    }
  }
}

// ---------------------------------------------------------------------------
// K5a: grouped expert GEMM, same structure, rows gathered via pairlist.
// ---------------------------------------------------------------------------
__global__ __launch_bounds__(256) void expert_gemm_mfma(const ushort* __restrict__ Ahi, const ushort* __restrict__ Alo,
                                                        const ushort* __restrict__ Bhi_all, const ushort* __restrict__ Blo_all,
                                                        const float* __restrict__ be1,
                                                        const int* __restrict__ counts,
                                                        const int* __restrict__ pairlist,
                                                        float* __restrict__ h1) {
  const int e = blockIdx.z;
  const int n_e = counts[e];
  const int m0 = blockIdx.y * 128;
  if (m0 >= n_e) return;
  const int n0 = blockIdx.x * 128;
  __shared__ __align__(16) ushort ldsAh[4096], ldsAl[4096], ldsBh[4096], ldsBl[4096];
  const int tid = threadIdx.x;
  const int lane = tid & 63, w = tid >> 6;
  const ushort* srcp[8];
  ushort* ldst;
  {
    const ushort* sbase;
    if (w < 2) {
      sbase = (w == 0) ? Ahi : Alo;
      ldst = (w == 0) ? ldsAh : ldsAl;
#pragma unroll
      for (int s = 0; s < 8; ++s) {
        int r = m0 + s * 16 + (lane & 15);
        if (r >= n_e) r = n_e - 1;
        int srow = pairlist[e * B_ + r] >> 2;   // sample index
        srcp[s] = sbase + (size_t)srow * H_ + ((lane >> 4) << 3);
      }
    } else {
      sbase = ((w == 2) ? Bhi_all : Blo_all) + (size_t)e * H_ * HID_;
      ldst = (w == 2) ? ldsBh : ldsBl;
#pragma unroll
      for (int s = 0; s < 8; ++s) {
        int col = n0 + s * 16 + (lane & 15);
        srcp[s] = sbase + (size_t)col * H_ + ((lane >> 4) << 3);
      }
    }
  }
  const int wr = w >> 1, wc = w & 1;
  f32x4 acc[4][4] = {};
  for (int k0 = 0; k0 < H_; k0 += 32) {
#pragma unroll
    for (int s = 0; s < 8; ++s)
      gload_lds16(srcp[s] + k0, ldst + s * 512);
    __syncthreads();
    bf16x8 ah[4], al[4], bh[4], bl[4];
#pragma unroll
    for (int i = 0; i < 4; ++i) {
      int off = (wr * 4 + i) * 512 + lane * 8;
      ah[i] = *(const bf16x8*)&ldsAh[off];
      al[i] = *(const bf16x8*)&ldsAl[off];
    }
#pragma unroll
    for (int j = 0; j < 4; ++j) {
      int off = (wc * 4 + j) * 512 + lane * 8;
      bh[j] = *(const bf16x8*)&ldsBh[off];
      bl[j] = *(const bf16x8*)&ldsBl[off];
    }
#pragma unroll
    for (int i = 0; i < 4; ++i)
#pragma unroll
      for (int j = 0; j < 4; ++j) {
        acc[i][j] = __builtin_amdgcn_mfma_f32_16x16x32_bf16(ah[i], bh[j], acc[i][j], 0, 0, 0);
        acc[i][j] = __builtin_amdgcn_mfma_f32_16x16x32_bf16(ah[i], bl[j], acc[i][j], 0, 0, 0);
        acc[i][j] = __builtin_amdgcn_mfma_f32_16x16x32_bf16(al[i], bh[j], acc[i][j], 0, 0, 0);
      }
    __syncthreads();
  }
  const int lr = (lane >> 4) << 2, lc = lane & 15;
#pragma unroll
  for (int i = 0; i < 4; ++i) {
    int pr[4]; bool ok[4];
#pragma unroll
    for (int r = 0; r < 4; ++r) {
      int li = m0 + wr * 64 + i * 16 + lr + r;
      ok[r] = li < n_e;
      pr[r] = pairlist[e * B_ + (ok[r] ? li : n_e - 1)];
    }
#pragma unroll
    for (int j = 0; j < 4; ++j) {
      int col = n0 + wc * 64 + j * 16 + lc;
      float bev = be1[e * HID_ + col];
#pragma unroll
      for (int r = 0; r < 4; ++r)
        if (ok[r]) h1[(size_t)pr[r] * HID_ + col] = acc[i][j][r] + bev;
    }
  }
}

// ---------------------------------------------------------------------------
// K4: original_logits = t @ Wo + bo. One wave per sample.
// ---------------------------------------------------------------------------
__global__ void ologits_kernel(const float* __restrict__ t, const float* __restrict__ Wo,
                               const float* __restrict__ bo, float* __restrict__ ol) {
  int b = blockIdx.x; int lane = threadIdx.x;
  const float* tr = t + (size_t)b * H_;
  float s0 = 0, s1 = 0, s2 = 0;
  for (int h = lane; h < H_; h += 64) {
    float v = tr[h];
    s0 = fmaf(v, Wo[h * 3 + 0], s0);
    s1 = fmaf(v, Wo[h * 3 + 1], s1);
    s2 = fmaf(v, Wo[h * 3 + 2], s2);
  }
#pragma unroll
  for (int off = 32; off; off >>= 1) {
    s0 += __shfl_down(s0, off); s1 += __shfl_down(s1, off); s2 += __shfl_down(s2, off);
  }
  if (lane == 0) {
    ol[b * 3 + 0] = s0 + bo[0]; ol[b * 3 + 1] = s1 + bo[1]; ol[b * 3 + 2] = s2 + bo[2];
  }
}

// ---------------------------------------------------------------------------
// K3c: Wcomb[e,d,:] = We2[e,d,:] @ Wp (We2->Wp collapse, no nonlinearity).
// ---------------------------------------------------------------------------
__global__ __launch_bounds__(256) void wcomb_kernel(const float* __restrict__ We2,
                                                    const float* __restrict__ Wp,
                                                    float* __restrict__ Wcomb) {
  const int row = blockIdx.x * 4 + (threadIdx.x >> 6);  // e*HID + d
  const int lane = threadIdx.x & 63;
  const float* wr = We2 + (size_t)row * HID_;
  float s0 = 0, s1 = 0, s2 = 0;
  for (int f = lane; f < HID_; f += 64) {
    float v = wr[f];
    s0 = fmaf(v, Wp[f * 3 + 0], s0);
    s1 = fmaf(v, Wp[f * 3 + 1], s1);
    s2 = fmaf(v, Wp[f * 3 + 2], s2);
  }
#pragma unroll
  for (int off = 32; off; off >>= 1) {
    s0 += __shfl_down(s0, off); s1 += __shfl_down(s1, off); s2 += __shfl_down(s2, off);
  }
  if (lane == 0) {
    Wcomb[row * 3 + 0] = s0; Wcomb[row * 3 + 1] = s1; Wcomb[row * 3 + 2] = s2;
  }
}

__global__ void bcomb_kernel(const float* __restrict__ be2, const float* __restrict__ Wp,
                             const float* __restrict__ bp, float* __restrict__ bcomb) {
  const int e = blockIdx.x; const int lane = threadIdx.x;
  const float* wr = be2 + (size_t)e * HID_;
  float s0 = 0, s1 = 0, s2 = 0;
  for (int f = lane; f < HID_; f += 64) {
    float v = wr[f];
    s0 = fmaf(v, Wp[f * 3 + 0], s0);
    s1 = fmaf(v, Wp[f * 3 + 1], s1);
    s2 = fmaf(v, Wp[f * 3 + 2], s2);
  }
#pragma unroll
  for (int off = 32; off; off >>= 1) {
    s0 += __shfl_down(s0, off); s1 += __shfl_down(s1, off); s2 += __shfl_down(s2, off);
  }
  if (lane == 0) {
    bcomb[e * 3 + 0] = s0 + bp[0]; bcomb[e * 3 + 1] = s1 + bp[1]; bcomb[e * 3 + 2] = s2 + bp[2];
  }
}

// ---------------------------------------------------------------------------
// K5b: per pair: LN + exact gelu + dot with Wcomb[e], scaled by prob.
// ---------------------------------------------------------------------------
__device__ __forceinline__ float blockSum256(float v, float* red) {
#pragma unroll
  for (int off = 32; off; off >>= 1) v += __shfl_down(v, off);
  const int wid = threadIdx.x >> 6;
  __syncthreads();
  if ((threadIdx.x & 63) == 0) red[wid] = v;
  __syncthreads();
  return red[0] + red[1] + red[2] + red[3];
}

__global__ __launch_bounds__(256) void lngelu_kernel(const float* __restrict__ h1,
                                                     const float* __restrict__ g1,
                                                     const float* __restrict__ beta1,
                                                     const int* __restrict__ topk_idx,
                                                     const float* __restrict__ topk_prob,
                                                     const float* __restrict__ Wcomb,
                                                     const float* __restrict__ bcomb,
                                                     float* __restrict__ contrib) {
  const int pair = blockIdx.x;
  const int e = topk_idx[pair];
  const float prob = topk_prob[pair];
  const int tid = threadIdx.x;
  __shared__ float red[4];
  float4 x = *(const float4*)&h1[(size_t)pair * HID_ + tid * 4];
  float s = x.x + x.y + x.z + x.w;
  s = blockSum256(s, red);
  const float mu = s * (1.0f / HID_);
  float dx = x.x - mu, dy = x.y - mu, dz = x.z - mu, dw = x.w - mu;
  float sq = dx * dx + dy * dy + dz * dz + dw * dw;
  sq = blockSum256(sq, red);
  const float inv = 1.0f / sqrtf(sq * (1.0f / HID_) + EPS_);
  const int d = tid * 4;
  float y[4] = {dx * inv, dy * inv, dz * inv, dw * inv};
  float c0 = 0, c1 = 0, c2 = 0;
#pragma unroll
  for (int i = 0; i < 4; ++i) {
    float g = g1[e * HID_ + d + i], bb = beta1[e * HID_ + d + i];
    float v = y[i] * g + bb;
    v = 0.5f * v * (1.0f + erff(v * 0.70710678118654752440f));  // exact gelu
    const float* wc = &Wcomb[(size_t)(e * HID_ + d + i) * 3];
    c0 = fmaf(v, wc[0], c0); c1 = fmaf(v, wc[1], c1); c2 = fmaf(v, wc[2], c2);
  }
  c0 = blockSum256(c0, red);
  c1 = blockSum256(c1, red);
  c2 = blockSum256(c2, red);
  if (tid == 0) {
    contrib[pair * 3 + 0] = prob * (c0 + bcomb[e * 3 + 0]);
    contrib[pair * 3 + 1] = prob * (c1 + bcomb[e * 3 + 1]);
    contrib[pair * 3 + 2] = prob * (c2 + bcomb[e * 3 + 2]);
  }
}

// ---------------------------------------------------------------------------
// K6: fixed-order k-sum, concat, 6->3, LN(3), relu, 3->3.
// ---------------------------------------------------------------------------
__global__ void final_kernel(const float* __restrict__ ol, const float* __restrict__ contrib,
                             const float* __restrict__ Wf1, const float* __restrict__ bf1,
                             const float* __restrict__ gf, const float* __restrict__ betaf,
                             const float* __restrict__ Wf2, const float* __restrict__ bf2,
                             float* __restrict__ out) {
  int b = blockIdx.x * blockDim.x + threadIdx.x;
  if (b >= B_) return;
  float comb[6];
  comb[0] = ol[b * 3 + 0]; comb[1] = ol[b * 3 + 1]; comb[2] = ol[b * 3 + 2];
  float mo0 = 0, mo1 = 0, mo2 = 0;
#pragma unroll
  for (int k = 0; k < K_; ++k) {
    mo0 += contrib[(b * K_ + k) * 3 + 0];
    mo1 += contrib[(b * K_ + k) * 3 + 1];
    mo2 += contrib[(b * K_ + k) * 3 + 2];
  }
  comb[3] = mo0; comb[4] = mo1; comb[5] = mo2;
  float z[3];
#pragma unroll
  for (int c = 0; c < 3; ++c) {
    float s = bf1[c];
#pragma unroll
    for (int i = 0; i < 6; ++i) s = fmaf(comb[i], Wf1[i * 3 + c], s);
    z[c] = s;
  }
  float mu = (z[0] + z[1] + z[2]) * (1.0f / 3.0f);
  float v0 = z[0] - mu, v1 = z[1] - mu, v2 = z[2] - mu;
  float var = (v0 * v0 + v1 * v1 + v2 * v2) * (1.0f / 3.0f);
  float inv = 1.0f / sqrtf(var + EPS_);
  float r[3];
#pragma unroll
  for (int c = 0; c < 3; ++c) {
    float zz = (z[c] - mu) * inv * gf[c] + betaf[c];
    r[c] = zz > 0.0f ? zz : 0.0f;
  }
#pragma unroll
  for (int c = 0; c < 3; ++c) {
    float s = bf2[c];
#pragma unroll
    for (int i = 0; i < 3; ++i) s = fmaf(r[i], Wf2[i * 3 + c], s);
    out[b * 3 + c] = s;
  }
}

// ---------------------------------------------------------------------------
extern "C" void kernel_launch(void* const* d_in, const int* in_sizes, int n_in,
                              void* d_out, int out_size, void* d_ws, size_t ws_size,
                              hipStream_t stream) {
  const float* hs    = (const float*)d_in[0];
  const float* Wd    = (const float*)d_in[1];
  const float* bd    = (const float*)d_in[2];
  const float* Wo    = (const float*)d_in[3];
  const float* bo    = (const float*)d_in[4];
  const float* Wr    = (const float*)d_in[5];
  const float* br    = (const float*)d_in[6];
  const float* We1   = (const float*)d_in[7];
  const float* be1   = (const float*)d_in[8];
  const float* g1    = (const float*)d_in[9];
  const float* beta1 = (const float*)d_in[10];
  const float* We2   = (const float*)d_in[11];
  const float* be2   = (const float*)d_in[12];
  const float* Wp    = (const float*)d_in[13];
  const float* bp    = (const float*)d_in[14];
  const float* Wf1   = (const float*)d_in[15];
  const float* bf1   = (const float*)d_in[16];
  const float* gf    = (const float*)d_in[17];
  const float* betaf = (const float*)d_in[18];
  const float* Wf2   = (const float*)d_in[19];
  const float* bf2   = (const float*)d_in[20];
  float* out = (float*)d_out;

  char* w = (char*)d_ws;
  size_t off = 0;
  auto alloc = [&](size_t bytes) {
    void* p = w + off;
    off = (off + bytes + 255) & ~(size_t)255;
    return p;
  };
  ushort* m_hi   = (ushort*)alloc((size_t)B_ * H_ * 2);
  ushort* m_lo   = (ushort*)alloc((size_t)B_ * H_ * 2);
  ushort* cls_hi = (ushort*)alloc((size_t)B_ * H_ * 2);
  ushort* cls_lo = (ushort*)alloc((size_t)B_ * H_ * 2);
  ushort* wd_hi  = (ushort*)alloc((size_t)H_ * H_ * 2);
  ushort* wd_lo  = (ushort*)alloc((size_t)H_ * H_ * 2);
  ushort* we1_hi = (ushort*)alloc((size_t)E_ * H_ * HID_ * 2);
  ushort* we1_lo = (ushort*)alloc((size_t)E_ * H_ * HID_ * 2);
  float* ws_t    = (float*)alloc((size_t)B_ * H_ * 4);
  float* ws_h1   = (float*)alloc((size_t)B_ * K_ * HID_ * 4);
  float* ws_wc   = (float*)alloc((size_t)E_ * HID_ * 3 * 4);
  float* ws_bc   = (float*)alloc(E_ * 3 * 4);
  float* ws_ol   = (float*)alloc(B_ * 3 * 4);
  float* ws_ctr  = (float*)alloc(B_ * K_ * 3 * 4);
  float* ws_prob = (float*)alloc(B_ * K_ * 4);
  int* ws_idx = (int*)alloc(B_ * K_ * 4);
  int* ws_cnt = (int*)alloc(E_ * 4);
  int* ws_pl  = (int*)alloc(E_ * B_ * 4);
  if (off > ws_size) return;

  hipMemsetAsync(ws_cnt, 0, E_ * sizeof(int), stream);

  wsplit_t_kernel<<<dim3(16, 16, 1), 256, 0, stream>>>(Wd, wd_hi, wd_lo);
  wsplit_t_kernel<<<dim3(16, 16, E_), 256, 0, stream>>>(We1, we1_hi, we1_lo);
  mean_cls_kernel<<<(B_ * H_ / 4) / 256, 256, 0, stream>>>(hs, m_hi, m_lo, cls_hi, cls_lo);
  router_kernel<<<B_, 64, 0, stream>>>(hs, Wr, br, ws_idx, ws_prob, ws_cnt, ws_pl);
  gemm_tanh_mfma<<<dim3(8, 8), 256, 0, stream>>>(cls_hi, cls_lo, wd_hi, wd_lo, bd, ws_t);
  ologits_kernel<<<B_, 64, 0, stream>>>(ws_t, Wo, bo, ws_ol);
  wcomb_kernel<<<E_ * HID_ / 4, 256, 0, stream>>>(We2, Wp, ws_wc);
  bcomb_kernel<<<E_, 64, 0, stream>>>(be2, Wp, bp, ws_bc);
  expert_gemm_mfma<<<dim3(8, 8, E_), 256, 0, stream>>>(m_hi, m_lo, we1_hi, we1_lo, be1, ws_cnt, ws_pl, ws_h1);
  lngelu_kernel<<<B_ * K_, 256, 0, stream>>>(ws_h1, g1, beta1, ws_idx, ws_prob, ws_wc, ws_bc, ws_ctr);
  final_kernel<<<(B_ + 255) / 256, 256, 0, stream>>>(ws_ol, ws_ctr, Wf1, bf1, gf, betaf, Wf2, bf2, out);
}

// Round 3
// 360.493 us; speedup vs baseline: 1.9088x; 1.2592x over previous
//
#include <hip/hip_runtime.h>
#include <math.h>

#define B_ 1024
#define S_ 128
#define H_ 1024
#define E_ 16
#define HID_ 1024
#define K_ 4
#define C_ 3
#define EPS_ 1e-5f

// prep kernel segment offsets (block ranges)
#define NB_MEAN 1024
#define NB_WD 256
#define NB_WE1 4096
#define NB_WC 4096
#define NB_RT 256
#define NB_BC 4
#define OFF_WD (NB_MEAN)
#define OFF_WE1 (OFF_WD + NB_WD)
#define OFF_WC (OFF_WE1 + NB_WE1)
#define OFF_RT (OFF_WC + NB_WC)
#define OFF_BC (OFF_RT + NB_RT)
#define NB_PREP (OFF_BC + NB_BC)

typedef __attribute__((ext_vector_type(8))) __bf16 bf16x8;
typedef __attribute__((ext_vector_type(4))) float f32x4;

__device__ __forceinline__ ushort bf16_rn(float f) {
  unsigned u = __float_as_uint(f);
  u += 0x7FFF + ((u >> 16) & 1);
  return (ushort)(u >> 16);
}
__device__ __forceinline__ float bf16_to_f(ushort h) {
  return __uint_as_float(((unsigned)h) << 16);
}
__device__ __forceinline__ void split2(float f, ushort& h, ushort& l) {
  h = bf16_rn(f);
  l = bf16_rn(f - bf16_to_f(h));
}
__device__ __forceinline__ void gload_lds16(const void* g, void* l) {
  __builtin_amdgcn_global_load_lds((const __attribute__((address_space(1))) void*)g,
                                   (__attribute__((address_space(3))) void*)l, 16, 0, 0);
}
__device__ __forceinline__ float waveRed3(float& s0, float& s1, float& s2) {
#pragma unroll
  for (int off = 32; off; off >>= 1) {
    s0 += __shfl_down(s0, off); s1 += __shfl_down(s1, off); s2 += __shfl_down(s2, off);
  }
  return s0;
}

// ---------------------------------------------------------------------------
// Phase A: prep mega-kernel. Independent segments by block range:
//   [0,1024)      mean+cls -> bf16 hi/lo splits
//   [1024,1280)   Wd transpose+split
//   [1280,5376)   We1 transpose+split (16 matrices)
//   [5376,9472)   Wcomb = We2 @ Wp (the We2->Wp algebraic collapse)
//   [9472,9728)   router: logits, top-4, softmax, expert pair lists
//   [9728,9732)   bcomb = be2 @ Wp + bp
// ---------------------------------------------------------------------------
__global__ __launch_bounds__(256) void prep_kernel(
    const float* __restrict__ hs,
    const float* __restrict__ Wd, const float* __restrict__ We1,
    const float* __restrict__ We2, const float* __restrict__ Wp, const float* __restrict__ bp,
    const float* __restrict__ Wr, const float* __restrict__ br,
    const float* __restrict__ be2,
    ushort* __restrict__ m_hi, ushort* __restrict__ m_lo,
    ushort* __restrict__ cls_hi, ushort* __restrict__ cls_lo,
    ushort* __restrict__ wd_hi, ushort* __restrict__ wd_lo,
    ushort* __restrict__ we1_hi, ushort* __restrict__ we1_lo,
    float* __restrict__ Wcomb, float* __restrict__ bcomb,
    int* __restrict__ topk_idx, float* __restrict__ topk_prob,
    int* __restrict__ counts, int* __restrict__ pairlist) {
  __shared__ float tbuf[64][65];
  const int blk = blockIdx.x;
  const int tid = threadIdx.x;

  if (blk < NB_MEAN) {
    // ---- mean over S + cls row, emit hi/lo bf16 splits ----
    int gid = blk * 256 + tid;
    int b = gid >> 8;
    int h4 = (gid & 255) << 2;
    const float* p = hs + (size_t)b * S_ * H_ + h4;
    float4 v0 = *(const float4*)p;
    float sx = v0.x, sy = v0.y, sz = v0.z, sw = v0.w;
#pragma unroll 4
    for (int s = 1; s < S_; ++s) {
      float4 v = *(const float4*)(p + (size_t)s * H_);
      sx += v.x; sy += v.y; sz += v.z; sw += v.w;
    }
    const float inv = 1.0f / (float)S_;
    float mv[4] = {sx * inv, sy * inv, sz * inv, sw * inv};
    float cv[4] = {v0.x, v0.y, v0.z, v0.w};
    ushort4 mh, ml, ch, cl;
    split2(mv[0], mh.x, ml.x); split2(mv[1], mh.y, ml.y); split2(mv[2], mh.z, ml.z); split2(mv[3], mh.w, ml.w);
    split2(cv[0], ch.x, cl.x); split2(cv[1], ch.y, cl.y); split2(cv[2], ch.z, cl.z); split2(cv[3], ch.w, cl.w);
    size_t o = (size_t)b * H_ + h4;
    *(ushort4*)&m_hi[o] = mh; *(ushort4*)&m_lo[o] = ml;
    *(ushort4*)&cls_hi[o] = ch; *(ushort4*)&cls_lo[o] = cl;
  } else if (blk < OFF_WC) {
    // ---- weight transpose + hi/lo split (Wd or one We1 expert) ----
    int t, zmat;
    const float* in;
    ushort *oh, *ol;
    if (blk < OFF_WE1) { t = blk - OFF_WD; zmat = 0; in = Wd; oh = wd_hi; ol = wd_lo; }
    else { int t2 = blk - OFF_WE1; zmat = t2 >> 8; t = t2 & 255; in = We1; oh = we1_hi; ol = we1_lo; }
    const int k0 = (t & 15) * 64, n0 = (t >> 4) * 64;
    const size_t mbase = (size_t)zmat * (1024 * 1024);
    const int c4 = (tid & 15) << 2;
    const int r0 = tid >> 4;
#pragma unroll
    for (int p = 0; p < 4; ++p) {
      int row = r0 + p * 16;
      float4 v = *(const float4*)&in[mbase + (size_t)(k0 + row) * 1024 + n0 + c4];
      tbuf[row][c4] = v.x; tbuf[row][c4 + 1] = v.y; tbuf[row][c4 + 2] = v.z; tbuf[row][c4 + 3] = v.w;
    }
    __syncthreads();
    const int k4 = (tid & 15) << 2;
#pragma unroll
    for (int p = 0; p < 4; ++p) {
      int n = r0 + p * 16;
      ushort4 hh, ll;
      split2(tbuf[k4 + 0][n], hh.x, ll.x);
      split2(tbuf[k4 + 1][n], hh.y, ll.y);
      split2(tbuf[k4 + 2][n], hh.z, ll.z);
      split2(tbuf[k4 + 3][n], hh.w, ll.w);
      size_t o = mbase + (size_t)(n0 + n) * 1024 + k0 + k4;
      *(ushort4*)&oh[o] = hh;
      *(ushort4*)&ol[o] = ll;
    }
  } else if (blk < OFF_RT) {
    // ---- Wcomb[e*HID+d,:] = We2[e,d,:] @ Wp ----
    const int row = (blk - OFF_WC) * 4 + (tid >> 6);
    const int lane = tid & 63;
    const float* wr = We2 + (size_t)row * HID_;
    float s0 = 0, s1 = 0, s2 = 0;
    for (int f = lane; f < HID_; f += 64) {
      float v = wr[f];
      s0 = fmaf(v, Wp[f * 3 + 0], s0);
      s1 = fmaf(v, Wp[f * 3 + 1], s1);
      s2 = fmaf(v, Wp[f * 3 + 2], s2);
    }
    waveRed3(s0, s1, s2);
    if (lane == 0) {
      Wcomb[row * 3 + 0] = s0; Wcomb[row * 3 + 1] = s1; Wcomb[row * 3 + 2] = s2;
    }
  } else if (blk < OFF_BC) {
    // ---- router: one wave per sample, 4 samples per block ----
    const int lane = tid & 63;
    const int b = (blk - OFF_RT) * 4 + (tid >> 6);
    const float* cls = hs + (size_t)b * S_ * H_;
    const int e = lane & 15, part = lane >> 4;
    float sum = 0.0f;
    for (int i = part * 256; i < part * 256 + 256; ++i)
      sum = fmaf(cls[i], Wr[i * E_ + e], sum);
    sum += __shfl_down(sum, 32);
    sum += __shfl_down(sum, 16);
    float lg[E_];
#pragma unroll
    for (int i = 0; i < E_; ++i) lg[i] = __shfl(sum, i);
    if (lane == 0) {
      for (int i = 0; i < E_; ++i) lg[i] += br[i];
      int idx[K_]; float tv[K_];
      for (int k = 0; k < K_; ++k) {
        int bi = 0; float bv = -1e30f;
        for (int i = 0; i < E_; ++i) { if (lg[i] > bv) { bv = lg[i]; bi = i; } }
        idx[k] = bi; tv[k] = bv; lg[bi] = -1e30f;
      }
      float mx = tv[0], ssum = 0.0f, p[K_];
      for (int k = 0; k < K_; ++k) { p[k] = expf(tv[k] - mx); ssum += p[k]; }
      for (int k = 0; k < K_; ++k) {
        p[k] /= ssum;
        topk_idx[b * K_ + k] = idx[k];
        topk_prob[b * K_ + k] = p[k];
        int pos = atomicAdd(&counts[idx[k]], 1);
        pairlist[idx[k] * B_ + pos] = b * K_ + k;
      }
    }
  } else {
    // ---- bcomb[e,:] = be2[e,:] @ Wp + bp ----
    const int e = (blk - OFF_BC) * 4 + (tid >> 6);
    const int lane = tid & 63;
    const float* wr = be2 + (size_t)e * HID_;
    float s0 = 0, s1 = 0, s2 = 0;
    for (int f = lane; f < HID_; f += 64) {
      float v = wr[f];
      s0 = fmaf(v, Wp[f * 3 + 0], s0);
      s1 = fmaf(v, Wp[f * 3 + 1], s1);
      s2 = fmaf(v, Wp[f * 3 + 2], s2);
    }
    waveRed3(s0, s1, s2);
    if (lane == 0) {
      bcomb[e * 3 + 0] = s0 + bp[0]; bcomb[e * 3 + 1] = s1 + bp[1]; bcomb[e * 3 + 2] = s2 + bp[2];
    }
  }
}

// ---------------------------------------------------------------------------
// Phase B: unified MFMA GEMM. z<16: grouped expert GEMM (rows gathered via
// pairlist, output h1 + be1). z==16: t = tanh(cls @ Wd + bd) -> ws_t.
// Split-bf16 3-MFMA (hh+hl+lh), 128x128 tile, BK=32, 4 waves (2x2 of 64x64).
// LDS is fragment-ordered 16x32 subtiles: global_load_lds lane order ==
// MFMA fragment layout -> lane-linear conflict-free ds_read_b128.
// ---------------------------------------------------------------------------
__global__ __launch_bounds__(256) void gemm_mega(
    const ushort* __restrict__ m_hi, const ushort* __restrict__ m_lo,
    const ushort* __restrict__ cls_hi, const ushort* __restrict__ cls_lo,
    const ushort* __restrict__ wd_hi, const ushort* __restrict__ wd_lo,
    const ushort* __restrict__ we1_hi, const ushort* __restrict__ we1_lo,
    const float* __restrict__ bd, const float* __restrict__ be1,
    const int* __restrict__ counts, const int* __restrict__ pairlist,
    float* __restrict__ ws_t, float* __restrict__ h1) {
  __shared__ __align__(16) ushort ldsAh[4096], ldsAl[4096], ldsBh[4096], ldsBl[4096];
  const int z = blockIdx.z;
  const int tid = threadIdx.x;
  const int lane = tid & 63, w = tid >> 6;
  const int m0 = blockIdx.y * 128, n0 = blockIdx.x * 128;
  const ushort* srcp[8];
  ushort* ldst = (w == 0) ? ldsAh : (w == 1) ? ldsAl : (w == 2) ? ldsBh : ldsBl;
  int n_e;
  if (z == 16) {
    n_e = B_;
    const ushort* sbase = (w == 0) ? cls_hi : (w == 1) ? cls_lo : (w == 2) ? wd_hi : wd_lo;
    const int base0 = (w < 2) ? m0 : n0;
#pragma unroll
    for (int s = 0; s < 8; ++s) {
      int idx = base0 + s * 16 + (lane & 15);
      srcp[s] = sbase + (size_t)idx * H_ + ((lane >> 4) << 3);
    }
  } else {
    n_e = counts[z];
    if (m0 >= n_e) return;
    if (w < 2) {
      const ushort* sbase = (w == 0) ? m_hi : m_lo;
#pragma unroll
      for (int s = 0; s < 8; ++s) {
        int r = m0 + s * 16 + (lane & 15);
        if (r >= n_e) r = n_e - 1;
        int srow = pairlist[z * B_ + r] >> 2;
        srcp[s] = sbase + (size_t)srow * H_ + ((lane >> 4) << 3);
      }
    } else {
      const ushort* sbase = ((w == 2) ? we1_hi : we1_lo) + (size_t)z * H_ * HID_;
#pragma unroll
      for (int s = 0; s < 8; ++s) {
        int col = n0 + s * 16 + (lane & 15);
        srcp[s] = sbase + (size_t)col * H_ + ((lane >> 4) << 3);
      }
    }
  }
  const int wr = w >> 1, wc = w & 1;
  f32x4 acc[4][4] = {};
  for (int k0 = 0; k0 < H_; k0 += 32) {
#pragma unroll
    for (int s = 0; s < 8; ++s)
      gload_lds16(srcp[s] + k0, ldst + s * 512);
    __syncthreads();
    bf16x8 ah[4], al[4], bh[4], bl[4];
#pragma unroll
    for (int i = 0; i < 4; ++i) {
      int off = (wr * 4 + i) * 512 + lane * 8;
      ah[i] = *(const bf16x8*)&ldsAh[off];
      al[i] = *(const bf16x8*)&ldsAl[off];
    }
#pragma unroll
    for (int j = 0; j < 4; ++j) {
      int off = (wc * 4 + j) * 512 + lane * 8;
      bh[j] = *(const bf16x8*)&ldsBh[off];
      bl[j] = *(const bf16x8*)&ldsBl[off];
    }
#pragma unroll
    for (int i = 0; i < 4; ++i)
#pragma unroll
      for (int j = 0; j < 4; ++j) {
        acc[i][j] = __builtin_amdgcn_mfma_f32_16x16x32_bf16(ah[i], bh[j], acc[i][j], 0, 0, 0);
        acc[i][j] = __builtin_amdgcn_mfma_f32_16x16x32_bf16(ah[i], bl[j], acc[i][j], 0, 0, 0);
        acc[i][j] = __builtin_amdgcn_mfma_f32_16x16x32_bf16(al[i], bh[j], acc[i][j], 0, 0, 0);
      }
    __syncthreads();
  }
  const int lr = (lane >> 4) << 2, lc = lane & 15;
  if (z == 16) {
#pragma unroll
    for (int i = 0; i < 4; ++i) {
      int row = m0 + wr * 64 + i * 16 + lr;
#pragma unroll
      for (int j = 0; j < 4; ++j) {
        int col = n0 + wc * 64 + j * 16 + lc;
        float bsv = bd[col];
#pragma unroll
        for (int r = 0; r < 4; ++r)
          ws_t[(size_t)(row + r) * H_ + col] = tanhf(acc[i][j][r] + bsv);
      }
    }
  } else {
#pragma unroll
    for (int i = 0; i < 4; ++i) {
      int pr[4]; bool ok[4];
#pragma unroll
      for (int r = 0; r < 4; ++r) {
        int li = m0 + wr * 64 + i * 16 + lr + r;
        ok[r] = li < n_e;
        pr[r] = pairlist[z * B_ + (ok[r] ? li : n_e - 1)];
      }
#pragma unroll
      for (int j = 0; j < 4; ++j) {
        int col = n0 + wc * 64 + j * 16 + lc;
        float bev = be1[z * HID_ + col];
#pragma unroll
        for (int r = 0; r < 4; ++r)
          if (ok[r]) h1[(size_t)pr[r] * HID_ + col] = acc[i][j][r] + bev;
      }
    }
  }
}

// ---------------------------------------------------------------------------
// Phase C: epilogue mega-kernel.
//   [0,256)      ologits: ol = t @ Wo + bo (one wave per sample)
//   [256,4352)   lngelu: per-pair LN + exact gelu + dot Wcomb[e] * prob
// ---------------------------------------------------------------------------
__device__ __forceinline__ float blockSum256(float v, float* red) {
#pragma unroll
  for (int off = 32; off; off >>= 1) v += __shfl_down(v, off);
  const int wid = threadIdx.x >> 6;
  __syncthreads();
  if ((threadIdx.x & 63) == 0) red[wid] = v;
  __syncthreads();
  return red[0] + red[1] + red[2] + red[3];
}

__global__ __launch_bounds__(256) void epi_kernel(
    const float* __restrict__ ws_t, const float* __restrict__ Wo, const float* __restrict__ bo,
    const float* __restrict__ h1, const float* __restrict__ g1, const float* __restrict__ beta1,
    const int* __restrict__ topk_idx, const float* __restrict__ topk_prob,
    const float* __restrict__ Wcomb, const float* __restrict__ bcomb,
    float* __restrict__ ol, float* __restrict__ contrib) {
  __shared__ float red[4];
  const int blk = blockIdx.x;
  const int tid = threadIdx.x;
  if (blk < 256) {
    const int lane = tid & 63;
    const int b = blk * 4 + (tid >> 6);
    const float* tr = ws_t + (size_t)b * H_;
    float s0 = 0, s1 = 0, s2 = 0;
    for (int h = lane; h < H_; h += 64) {
      float v = tr[h];
      s0 = fmaf(v, Wo[h * 3 + 0], s0);
      s1 = fmaf(v, Wo[h * 3 + 1], s1);
      s2 = fmaf(v, Wo[h * 3 + 2], s2);
    }
    waveRed3(s0, s1, s2);
    if (lane == 0) {
      ol[b * 3 + 0] = s0 + bo[0]; ol[b * 3 + 1] = s1 + bo[1]; ol[b * 3 + 2] = s2 + bo[2];
    }
  } else {
    const int pair = blk - 256;
    const int e = topk_idx[pair];
    const float prob = topk_prob[pair];
    float4 x = *(const float4*)&h1[(size_t)pair * HID_ + tid * 4];
    float s = x.x + x.y + x.z + x.w;
    s = blockSum256(s, red);
    const float mu = s * (1.0f / HID_);
    float dx = x.x - mu, dy = x.y - mu, dz = x.z - mu, dw = x.w - mu;
    float sq = dx * dx + dy * dy + dz * dz + dw * dw;
    sq = blockSum256(sq, red);
    const float inv = 1.0f / sqrtf(sq * (1.0f / HID_) + EPS_);
    const int d = tid * 4;
    float y[4] = {dx * inv, dy * inv, dz * inv, dw * inv};
    float c0 = 0, c1 = 0, c2 = 0;
#pragma unroll
    for (int i = 0; i < 4; ++i) {
      float g = g1[e * HID_ + d + i], bb = beta1[e * HID_ + d + i];
      float v = y[i] * g + bb;
      v = 0.5f * v * (1.0f + erff(v * 0.70710678118654752440f));
      const float* wc = &Wcomb[(size_t)(e * HID_ + d + i) * 3];
      c0 = fmaf(v, wc[0], c0); c1 = fmaf(v, wc[1], c1); c2 = fmaf(v, wc[2], c2);
    }
    c0 = blockSum256(c0, red);
    c1 = blockSum256(c1, red);
    c2 = blockSum256(c2, red);
    if (tid == 0) {
      contrib[pair * 3 + 0] = prob * (c0 + bcomb[e * 3 + 0]);
      contrib[pair * 3 + 1] = prob * (c1 + bcomb[e * 3 + 1]);
      contrib[pair * 3 + 2] = prob * (c2 + bcomb[e * 3 + 2]);
    }
  }
}

// ---------------------------------------------------------------------------
// Phase D: fixed-order k-sum, concat, 6->3, LN(3), relu, 3->3.
// ---------------------------------------------------------------------------
__global__ void final_kernel(const float* __restrict__ ol, const float* __restrict__ contrib,
                             const float* __restrict__ Wf1, const float* __restrict__ bf1,
                             const float* __restrict__ gf, const float* __restrict__ betaf,
                             const float* __restrict__ Wf2, const float* __restrict__ bf2,
                             float* __restrict__ out) {
  int b = blockIdx.x * blockDim.x + threadIdx.x;
  if (b >= B_) return;
  float comb[6];
  comb[0] = ol[b * 3 + 0]; comb[1] = ol[b * 3 + 1]; comb[2] = ol[b * 3 + 2];
  float mo0 = 0, mo1 = 0, mo2 = 0;
#pragma unroll
  for (int k = 0; k < K_; ++k) {
    mo0 += contrib[(b * K_ + k) * 3 + 0];
    mo1 += contrib[(b * K_ + k) * 3 + 1];
    mo2 += contrib[(b * K_ + k) * 3 + 2];
  }
  comb[3] = mo0; comb[4] = mo1; comb[5] = mo2;
  float z[3];
#pragma unroll
  for (int c = 0; c < 3; ++c) {
    float s = bf1[c];
#pragma unroll
    for (int i = 0; i < 6; ++i) s = fmaf(comb[i], Wf1[i * 3 + c], s);
    z[c] = s;
  }
  float mu = (z[0] + z[1] + z[2]) * (1.0f / 3.0f);
  float v0 = z[0] - mu, v1 = z[1] - mu, v2 = z[2] - mu;
  float var = (v0 * v0 + v1 * v1 + v2 * v2) * (1.0f / 3.0f);
  float inv = 1.0f / sqrtf(var + EPS_);
  float r[3];
#pragma unroll
  for (int c = 0; c < 3; ++c) {
    float zz = (z[c] - mu) * inv * gf[c] + betaf[c];
    r[c] = zz > 0.0f ? zz : 0.0f;
  }
#pragma unroll
  for (int c = 0; c < 3; ++c) {
    float s = bf2[c];
#pragma unroll
    for (int i = 0; i < 3; ++i) s = fmaf(r[i], Wf2[i * 3 + c], s);
    out[b * 3 + c] = s;
  }
}

// ---------------------------------------------------------------------------
extern "C" void kernel_launch(void* const* d_in, const int* in_sizes, int n_in,
                              void* d_out, int out_size, void* d_ws, size_t ws_size,
                              hipStream_t stream) {
  const float* hs    = (const float*)d_in[0];
  const float* Wd    = (const float*)d_in[1];
  const float* bd    = (const float*)d_in[2];
  const float* Wo    = (const float*)d_in[3];
  const float* bo    = (const float*)d_in[4];
  const float* Wr    = (const float*)d_in[5];
  const float* br    = (const float*)d_in[6];
  const float* We1   = (const float*)d_in[7];
  const float* be1   = (const float*)d_in[8];
  const float* g1    = (const float*)d_in[9];
  const float* beta1 = (const float*)d_in[10];
  const float* We2   = (const float*)d_in[11];
  const float* be2   = (const float*)d_in[12];
  const float* Wp    = (const float*)d_in[13];
  const float* bp    = (const float*)d_in[14];
  const float* Wf1   = (const float*)d_in[15];
  const float* bf1   = (const float*)d_in[16];
  const float* gf    = (const float*)d_in[17];
  const float* betaf = (const float*)d_in[18];
  const float* Wf2   = (const float*)d_in[19];
  const float* bf2   = (const float*)d_in[20];
  float* out = (float*)d_out;

  char* w = (char*)d_ws;
  size_t off = 0;
  auto alloc = [&](size_t bytes) {
    void* p = w + off;
    off = (off + bytes + 255) & ~(size_t)255;
    return p;
  };
  ushort* m_hi   = (ushort*)alloc((size_t)B_ * H_ * 2);
  ushort* m_lo   = (ushort*)alloc((size_t)B_ * H_ * 2);
  ushort* cls_hi = (ushort*)alloc((size_t)B_ * H_ * 2);
  ushort* cls_lo = (ushort*)alloc((size_t)B_ * H_ * 2);
  ushort* wd_hi  = (ushort*)alloc((size_t)H_ * H_ * 2);
  ushort* wd_lo  = (ushort*)alloc((size_t)H_ * H_ * 2);
  ushort* we1_hi = (ushort*)alloc((size_t)E_ * H_ * HID_ * 2);
  ushort* we1_lo = (ushort*)alloc((size_t)E_ * H_ * HID_ * 2);
  float* ws_t    = (float*)alloc((size_t)B_ * H_ * 4);
  float* ws_h1   = (float*)alloc((size_t)B_ * K_ * HID_ * 4);
  float* ws_wc   = (float*)alloc((size_t)E_ * HID_ * 3 * 4);
  float* ws_bc   = (float*)alloc(E_ * 3 * 4);
  float* ws_ol   = (float*)alloc(B_ * 3 * 4);
  float* ws_ctr  = (float*)alloc(B_ * K_ * 3 * 4);
  float* ws_prob = (float*)alloc(B_ * K_ * 4);
  int* ws_idx = (int*)alloc(B_ * K_ * 4);
  int* ws_cnt = (int*)alloc(E_ * 4);
  int* ws_pl  = (int*)alloc(E_ * B_ * 4);
  if (off > ws_size) return;

  hipMemsetAsync(ws_cnt, 0, E_ * sizeof(int), stream);

  prep_kernel<<<NB_PREP, 256, 0, stream>>>(hs, Wd, We1, We2, Wp, bp, Wr, br, be2,
                                           m_hi, m_lo, cls_hi, cls_lo, wd_hi, wd_lo,
                                           we1_hi, we1_lo, ws_wc, ws_bc,
                                           ws_idx, ws_prob, ws_cnt, ws_pl);
  gemm_mega<<<dim3(8, 8, 17), 256, 0, stream>>>(m_hi, m_lo, cls_hi, cls_lo,
                                                wd_hi, wd_lo, we1_hi, we1_lo,
                                                bd, be1, ws_cnt, ws_pl, ws_t, ws_h1);
  epi_kernel<<<256 + B_ * K_, 256, 0, stream>>>(ws_t, Wo, bo, ws_h1, g1, beta1,
                                                ws_idx, ws_prob, ws_wc, ws_bc, ws_ol, ws_ctr);
  final_kernel<<<(B_ + 255) / 256, 256, 0, stream>>>(ws_ol, ws_ctr, Wf1, bf1, gf, betaf, Wf2, bf2, out);
}

// Round 4
// 353.252 us; speedup vs baseline: 1.9479x; 1.0205x over previous
//
#include <hip/hip_runtime.h>
#include <math.h>

#define B_ 1024
#define S_ 128
#define H_ 1024
#define E_ 16
#define HID_ 1024
#define K_ 4
#define C_ 3
#define EPS_ 1e-5f

// prep kernel segment offsets (block ranges)
#define NB_MEAN 1024
#define NB_WD 256
#define NB_WE1 4096
#define NB_WC 4096
#define NB_RT 256
#define NB_BC 4
#define OFF_WD (NB_MEAN)
#define OFF_WE1 (OFF_WD + NB_WD)
#define OFF_WC (OFF_WE1 + NB_WE1)
#define OFF_RT (OFF_WC + NB_WC)
#define OFF_BC (OFF_RT + NB_RT)
#define NB_PREP (OFF_BC + NB_BC)

typedef __attribute__((ext_vector_type(8))) __bf16 bf16x8;
typedef __attribute__((ext_vector_type(4))) float f32x4;

__device__ __forceinline__ ushort bf16_rn(float f) {
  unsigned u = __float_as_uint(f);
  u += 0x7FFF + ((u >> 16) & 1);
  return (ushort)(u >> 16);
}
__device__ __forceinline__ float bf16_to_f(ushort h) {
  return __uint_as_float(((unsigned)h) << 16);
}
__device__ __forceinline__ void split2(float f, ushort& h, ushort& l) {
  h = bf16_rn(f);
  l = bf16_rn(f - bf16_to_f(h));
}
__device__ __forceinline__ void gload_lds16(const void* g, void* l) {
  __builtin_amdgcn_global_load_lds((const __attribute__((address_space(1))) void*)g,
                                   (__attribute__((address_space(3))) void*)l, 16, 0, 0);
}
__device__ __forceinline__ void waveRed3(float& s0, float& s1, float& s2) {
#pragma unroll
  for (int off = 32; off; off >>= 1) {
    s0 += __shfl_down(s0, off); s1 += __shfl_down(s1, off); s2 += __shfl_down(s2, off);
  }
}

// ---------------------------------------------------------------------------
// Phase A: prep mega-kernel. Independent segments by block range:
//   [0,1024)      mean+cls -> bf16 hi/lo splits
//   [1024,1280)   Wd transpose+split
//   [1280,5376)   We1 transpose+split (16 matrices)
//   [5376,9472)   Wcomb = We2 @ Wp (the We2->Wp algebraic collapse)
//   [9472,9728)   router: logits, top-4, softmax, expert pair lists
//   [9728,9732)   bcomb = be2 @ Wp + bp
// ---------------------------------------------------------------------------
__global__ __launch_bounds__(256) void prep_kernel(
    const float* __restrict__ hs,
    const float* __restrict__ Wd, const float* __restrict__ We1,
    const float* __restrict__ We2, const float* __restrict__ Wp, const float* __restrict__ bp,
    const float* __restrict__ Wr, const float* __restrict__ br,
    const float* __restrict__ be2,
    ushort* __restrict__ m_hi, ushort* __restrict__ m_lo,
    ushort* __restrict__ cls_hi, ushort* __restrict__ cls_lo,
    ushort* __restrict__ wd_hi, ushort* __restrict__ wd_lo,
    ushort* __restrict__ we1_hi, ushort* __restrict__ we1_lo,
    float* __restrict__ Wcomb, float* __restrict__ bcomb,
    int* __restrict__ topk_idx, float* __restrict__ topk_prob,
    int* __restrict__ counts, int* __restrict__ pairlist) {
  __shared__ float tbuf[64][65];
  const int blk = blockIdx.x;
  const int tid = threadIdx.x;

  if (blk < NB_MEAN) {
    // ---- mean over S + cls row, emit hi/lo bf16 splits ----
    int gid = blk * 256 + tid;
    int b = gid >> 8;
    int h4 = (gid & 255) << 2;
    const float* p = hs + (size_t)b * S_ * H_ + h4;
    float4 v0 = *(const float4*)p;
    float sx = v0.x, sy = v0.y, sz = v0.z, sw = v0.w;
    // s=1..127, unroll 8 for deep outstanding-load pipeline
#pragma unroll 8
    for (int s = 1; s < S_; ++s) {
      float4 v = *(const float4*)(p + (size_t)s * H_);
      sx += v.x; sy += v.y; sz += v.z; sw += v.w;
    }
    const float inv = 1.0f / (float)S_;
    float mv[4] = {sx * inv, sy * inv, sz * inv, sw * inv};
    float cv[4] = {v0.x, v0.y, v0.z, v0.w};
    ushort4 mh, ml, ch, cl;
    split2(mv[0], mh.x, ml.x); split2(mv[1], mh.y, ml.y); split2(mv[2], mh.z, ml.z); split2(mv[3], mh.w, ml.w);
    split2(cv[0], ch.x, cl.x); split2(cv[1], ch.y, cl.y); split2(cv[2], ch.z, cl.z); split2(cv[3], ch.w, cl.w);
    size_t o = (size_t)b * H_ + h4;
    *(ushort4*)&m_hi[o] = mh; *(ushort4*)&m_lo[o] = ml;
    *(ushort4*)&cls_hi[o] = ch; *(ushort4*)&cls_lo[o] = cl;
  } else if (blk < OFF_WC) {
    // ---- weight transpose + hi/lo split (Wd or one We1 expert) ----
    int t, zmat;
    const float* in;
    ushort *oh, *ol;
    if (blk < OFF_WE1) { t = blk - OFF_WD; zmat = 0; in = Wd; oh = wd_hi; ol = wd_lo; }
    else { int t2 = blk - OFF_WE1; zmat = t2 >> 8; t = t2 & 255; in = We1; oh = we1_hi; ol = we1_lo; }
    const int k0 = (t & 15) * 64, n0 = (t >> 4) * 64;
    const size_t mbase = (size_t)zmat * (1024 * 1024);
    const int c4 = (tid & 15) << 2;
    const int r0 = tid >> 4;
#pragma unroll
    for (int p = 0; p < 4; ++p) {
      int row = r0 + p * 16;
      float4 v = *(const float4*)&in[mbase + (size_t)(k0 + row) * 1024 + n0 + c4];
      tbuf[row][c4] = v.x; tbuf[row][c4 + 1] = v.y; tbuf[row][c4 + 2] = v.z; tbuf[row][c4 + 3] = v.w;
    }
    __syncthreads();
    const int k4 = (tid & 15) << 2;
#pragma unroll
    for (int p = 0; p < 4; ++p) {
      int n = r0 + p * 16;
      ushort4 hh, ll;
      split2(tbuf[k4 + 0][n], hh.x, ll.x);
      split2(tbuf[k4 + 1][n], hh.y, ll.y);
      split2(tbuf[k4 + 2][n], hh.z, ll.z);
      split2(tbuf[k4 + 3][n], hh.w, ll.w);
      size_t o = mbase + (size_t)(n0 + n) * 1024 + k0 + k4;
      *(ushort4*)&oh[o] = hh;
      *(ushort4*)&ol[o] = ll;
    }
  } else if (blk < OFF_RT) {
    // ---- Wcomb[e*HID+d,:] = We2[e,d,:] @ Wp ----
    const int row = (blk - OFF_WC) * 4 + (tid >> 6);
    const int lane = tid & 63;
    const float* wr = We2 + (size_t)row * HID_;
    float s0 = 0, s1 = 0, s2 = 0;
    for (int f = lane; f < HID_; f += 64) {
      float v = wr[f];
      s0 = fmaf(v, Wp[f * 3 + 0], s0);
      s1 = fmaf(v, Wp[f * 3 + 1], s1);
      s2 = fmaf(v, Wp[f * 3 + 2], s2);
    }
    waveRed3(s0, s1, s2);
    if (lane == 0) {
      Wcomb[row * 3 + 0] = s0; Wcomb[row * 3 + 1] = s1; Wcomb[row * 3 + 2] = s2;
    }
  } else if (blk < OFF_BC) {
    // ---- router: one wave per sample, 4 samples per block ----
    const int lane = tid & 63;
    const int b = (blk - OFF_RT) * 4 + (tid >> 6);
    const float* cls = hs + (size_t)b * S_ * H_;
    const int e = lane & 15, part = lane >> 4;
    float sum = 0.0f;
    for (int i = part * 256; i < part * 256 + 256; ++i)
      sum = fmaf(cls[i], Wr[i * E_ + e], sum);
    sum += __shfl_down(sum, 32);
    sum += __shfl_down(sum, 16);
    float lg[E_];
#pragma unroll
    for (int i = 0; i < E_; ++i) lg[i] = __shfl(sum, i);
    if (lane == 0) {
      for (int i = 0; i < E_; ++i) lg[i] += br[i];
      int idx[K_]; float tv[K_];
      for (int k = 0; k < K_; ++k) {
        int bi = 0; float bv = -1e30f;
        for (int i = 0; i < E_; ++i) { if (lg[i] > bv) { bv = lg[i]; bi = i; } }
        idx[k] = bi; tv[k] = bv; lg[bi] = -1e30f;
      }
      float mx = tv[0], ssum = 0.0f, p[K_];
      for (int k = 0; k < K_; ++k) { p[k] = expf(tv[k] - mx); ssum += p[k]; }
      for (int k = 0; k < K_; ++k) {
        p[k] /= ssum;
        topk_idx[b * K_ + k] = idx[k];
        topk_prob[b * K_ + k] = p[k];
        int pos = atomicAdd(&counts[idx[k]], 1);
        pairlist[idx[k] * B_ + pos] = b * K_ + k;
      }
    }
  } else {
    // ---- bcomb[e,:] = be2[e,:] @ Wp + bp ----
    const int e = (blk - OFF_BC) * 4 + (tid >> 6);
    const int lane = tid & 63;
    const float* wr = be2 + (size_t)e * HID_;
    float s0 = 0, s1 = 0, s2 = 0;
    for (int f = lane; f < HID_; f += 64) {
      float v = wr[f];
      s0 = fmaf(v, Wp[f * 3 + 0], s0);
      s1 = fmaf(v, Wp[f * 3 + 1], s1);
      s2 = fmaf(v, Wp[f * 3 + 2], s2);
    }
    waveRed3(s0, s1, s2);
    if (lane == 0) {
      bcomb[e * 3 + 0] = s0 + bp[0]; bcomb[e * 3 + 1] = s1 + bp[1]; bcomb[e * 3 + 2] = s2 + bp[2];
    }
  }
}

// ---------------------------------------------------------------------------
// Phase B: unified MFMA GEMM. z<16: grouped expert GEMM (rows gathered via
// pairlist, output h1 + be1). z==16: t = tanh(cls @ Wd + bd) -> ws_t.
// Split-bf16 3-MFMA (hh+hl+lh), 128x128 tile, BK=32, 4 waves (2x2 of 64x64).
// LDS is fragment-ordered 16x32 subtiles: global_load_lds lane order ==
// MFMA fragment layout -> lane-linear conflict-free ds_read_b128.
// ---------------------------------------------------------------------------
__global__ __launch_bounds__(256) void gemm_mega(
    const ushort* __restrict__ m_hi, const ushort* __restrict__ m_lo,
    const ushort* __restrict__ cls_hi, const ushort* __restrict__ cls_lo,
    const ushort* __restrict__ wd_hi, const ushort* __restrict__ wd_lo,
    const ushort* __restrict__ we1_hi, const ushort* __restrict__ we1_lo,
    const float* __restrict__ bd, const float* __restrict__ be1,
    const int* __restrict__ counts, const int* __restrict__ pairlist,
    float* __restrict__ ws_t, float* __restrict__ h1) {
  __shared__ __align__(16) ushort ldsAh[4096], ldsAl[4096], ldsBh[4096], ldsBl[4096];
  const int z = blockIdx.z;
  const int tid = threadIdx.x;
  const int lane = tid & 63, w = tid >> 6;
  const int m0 = blockIdx.y * 128, n0 = blockIdx.x * 128;
  const ushort* srcp[8];
  ushort* ldst = (w == 0) ? ldsAh : (w == 1) ? ldsAl : (w == 2) ? ldsBh : ldsBl;
  int n_e;
  if (z == 16) {
    n_e = B_;
    const ushort* sbase = (w == 0) ? cls_hi : (w == 1) ? cls_lo : (w == 2) ? wd_hi : wd_lo;
    const int base0 = (w < 2) ? m0 : n0;
#pragma unroll
    for (int s = 0; s < 8; ++s) {
      int idx = base0 + s * 16 + (lane & 15);
      srcp[s] = sbase + (size_t)idx * H_ + ((lane >> 4) << 3);
    }
  } else {
    n_e = counts[z];
    if (m0 >= n_e) return;
    if (w < 2) {
      const ushort* sbase = (w == 0) ? m_hi : m_lo;
#pragma unroll
      for (int s = 0; s < 8; ++s) {
        int r = m0 + s * 16 + (lane & 15);
        if (r >= n_e) r = n_e - 1;
        int srow = pairlist[z * B_ + r] >> 2;
        srcp[s] = sbase + (size_t)srow * H_ + ((lane >> 4) << 3);
      }
    } else {
      const ushort* sbase = ((w == 2) ? we1_hi : we1_lo) + (size_t)z * H_ * HID_;
#pragma unroll
      for (int s = 0; s < 8; ++s) {
        int col = n0 + s * 16 + (lane & 15);
        srcp[s] = sbase + (size_t)col * H_ + ((lane >> 4) << 3);
      }
    }
  }
  const int wr = w >> 1, wc = w & 1;
  f32x4 acc[4][4] = {};
  for (int k0 = 0; k0 < H_; k0 += 32) {
#pragma unroll
    for (int s = 0; s < 8; ++s)
      gload_lds16(srcp[s] + k0, ldst + s * 512);
    __syncthreads();
    bf16x8 ah[4], al[4], bh[4], bl[4];
#pragma unroll
    for (int i = 0; i < 4; ++i) {
      int off = (wr * 4 + i) * 512 + lane * 8;
      ah[i] = *(const bf16x8*)&ldsAh[off];
      al[i] = *(const bf16x8*)&ldsAl[off];
    }
#pragma unroll
    for (int j = 0; j < 4; ++j) {
      int off = (wc * 4 + j) * 512 + lane * 8;
      bh[j] = *(const bf16x8*)&ldsBh[off];
      bl[j] = *(const bf16x8*)&ldsBl[off];
    }
#pragma unroll
    for (int i = 0; i < 4; ++i)
#pragma unroll
      for (int j = 0; j < 4; ++j) {
        acc[i][j] = __builtin_amdgcn_mfma_f32_16x16x32_bf16(ah[i], bh[j], acc[i][j], 0, 0, 0);
        acc[i][j] = __builtin_amdgcn_mfma_f32_16x16x32_bf16(ah[i], bl[j], acc[i][j], 0, 0, 0);
        acc[i][j] = __builtin_amdgcn_mfma_f32_16x16x32_bf16(al[i], bh[j], acc[i][j], 0, 0, 0);
      }
    __syncthreads();
  }
  const int lr = (lane >> 4) << 2, lc = lane & 15;
  if (z == 16) {
#pragma unroll
    for (int i = 0; i < 4; ++i) {
      int row = m0 + wr * 64 + i * 16 + lr;
#pragma unroll
      for (int j = 0; j < 4; ++j) {
        int col = n0 + wc * 64 + j * 16 + lc;
        float bsv = bd[col];
#pragma unroll
        for (int r = 0; r < 4; ++r)
          ws_t[(size_t)(row + r) * H_ + col] = tanhf(acc[i][j][r] + bsv);
      }
    }
  } else {
#pragma unroll
    for (int i = 0; i < 4; ++i) {
      int pr[4]; bool ok[4];
#pragma unroll
      for (int r = 0; r < 4; ++r) {
        int li = m0 + wr * 64 + i * 16 + lr + r;
        ok[r] = li < n_e;
        pr[r] = pairlist[z * B_ + (ok[r] ? li : n_e - 1)];
      }
#pragma unroll
      for (int j = 0; j < 4; ++j) {
        int col = n0 + wc * 64 + j * 16 + lc;
        float bev = be1[z * HID_ + col];
#pragma unroll
        for (int r = 0; r < 4; ++r)
          if (ok[r]) h1[(size_t)pr[r] * HID_ + col] = acc[i][j][r] + bev;
      }
    }
  }
}

// ---------------------------------------------------------------------------
// Phase C: fully fused epilogue. One block per sample b (256 thr = 4 waves).
// Wave w handles pair b*4+w: LN(h1) -> exact gelu -> dot Wcomb[e] * prob.
// All 4 waves also compute a 256-chunk partial of ologits = t[b] @ Wo.
// Cross-wave combine in LDS (fixed order -> deterministic), then thread 0
// does concat -> 6x3 -> LN(3) -> relu -> 3x3 -> out[b].
// ---------------------------------------------------------------------------
__global__ __launch_bounds__(256) void epi_kernel(
    const float* __restrict__ ws_t, const float* __restrict__ Wo, const float* __restrict__ bo,
    const float* __restrict__ h1, const float* __restrict__ g1, const float* __restrict__ beta1,
    const int* __restrict__ topk_idx, const float* __restrict__ topk_prob,
    const float* __restrict__ Wcomb, const float* __restrict__ bcomb,
    const float* __restrict__ Wf1, const float* __restrict__ bf1,
    const float* __restrict__ gf, const float* __restrict__ betaf,
    const float* __restrict__ Wf2, const float* __restrict__ bf2,
    float* __restrict__ out) {
  const int b = blockIdx.x;
  const int tid = threadIdx.x;
  const int w = tid >> 6, lane = tid & 63;
  __shared__ float sCtr[4][3];
  __shared__ float sOl[4][3];

  // ---- per-wave: expert pair LN + gelu + Wcomb dot ----
  const int pair = b * K_ + w;
  const int e = topk_idx[pair];
  const float prob = topk_prob[pair];
  const float* hrow = h1 + (size_t)pair * HID_;
  float4 x[4];
#pragma unroll
  for (int q = 0; q < 4; ++q) x[q] = *(const float4*)&hrow[q * 256 + lane * 4];
  float s = 0;
#pragma unroll
  for (int q = 0; q < 4; ++q) s += x[q].x + x[q].y + x[q].z + x[q].w;
#pragma unroll
  for (int off = 32; off; off >>= 1) s += __shfl_down(s, off);
  const float mu = __shfl(s, 0) * (1.0f / HID_);
  float sq = 0;
#pragma unroll
  for (int q = 0; q < 4; ++q) {
    float dx = x[q].x - mu, dy = x[q].y - mu, dz = x[q].z - mu, dw = x[q].w - mu;
    sq += dx * dx + dy * dy + dz * dz + dw * dw;
  }
#pragma unroll
  for (int off = 32; off; off >>= 1) sq += __shfl_down(sq, off);
  const float inv = 1.0f / sqrtf(__shfl(sq, 0) * (1.0f / HID_) + EPS_);
  float c0 = 0, c1 = 0, c2 = 0;
#pragma unroll
  for (int q = 0; q < 4; ++q) {
    const int d = q * 256 + lane * 4;
    float4 gg = *(const float4*)&g1[(size_t)e * HID_ + d];
    float4 bb = *(const float4*)&beta1[(size_t)e * HID_ + d];
    float xv[4] = {x[q].x, x[q].y, x[q].z, x[q].w};
    float gv[4] = {gg.x, gg.y, gg.z, gg.w};
    float bv[4] = {bb.x, bb.y, bb.z, bb.w};
#pragma unroll
    for (int i = 0; i < 4; ++i) {
      float v = (xv[i] - mu) * inv * gv[i] + bv[i];
      v = 0.5f * v * (1.0f + erff(v * 0.70710678118654752440f));  // exact gelu
      const float* wc = &Wcomb[(size_t)(e * HID_ + d + i) * 3];
      c0 = fmaf(v, wc[0], c0); c1 = fmaf(v, wc[1], c1); c2 = fmaf(v, wc[2], c2);
    }
  }
  waveRed3(c0, c1, c2);
  if (lane == 0) {
    sCtr[w][0] = prob * (c0 + bcomb[e * 3 + 0]);
    sCtr[w][1] = prob * (c1 + bcomb[e * 3 + 1]);
    sCtr[w][2] = prob * (c2 + bcomb[e * 3 + 2]);
  }

  // ---- per-wave: 256-chunk partial of ologits ----
  {
    const float* tr = ws_t + (size_t)b * H_ + w * 256;
    float4 tv = *(const float4*)&tr[lane * 4];
    float o0 = 0, o1 = 0, o2 = 0;
    float tvv[4] = {tv.x, tv.y, tv.z, tv.w};
#pragma unroll
    for (int i = 0; i < 4; ++i) {
      const float* wo = &Wo[(size_t)(w * 256 + lane * 4 + i) * 3];
      o0 = fmaf(tvv[i], wo[0], o0); o1 = fmaf(tvv[i], wo[1], o1); o2 = fmaf(tvv[i], wo[2], o2);
    }
    waveRed3(o0, o1, o2);
    if (lane == 0) { sOl[w][0] = o0; sOl[w][1] = o1; sOl[w][2] = o2; }
  }
  __syncthreads();

  // ---- thread 0: combine + final head ----
  if (tid == 0) {
    float comb[6];
#pragma unroll
    for (int c = 0; c < 3; ++c) {
      comb[c] = sOl[0][c] + sOl[1][c] + sOl[2][c] + sOl[3][c] + bo[c];
      comb[3 + c] = sCtr[0][c] + sCtr[1][c] + sCtr[2][c] + sCtr[3][c];
    }
    float z[3];
#pragma unroll
    for (int c = 0; c < 3; ++c) {
      float sv = bf1[c];
#pragma unroll
      for (int i = 0; i < 6; ++i) sv = fmaf(comb[i], Wf1[i * 3 + c], sv);
      z[c] = sv;
    }
    float mu3 = (z[0] + z[1] + z[2]) * (1.0f / 3.0f);
    float v0 = z[0] - mu3, v1 = z[1] - mu3, v2 = z[2] - mu3;
    float var = (v0 * v0 + v1 * v1 + v2 * v2) * (1.0f / 3.0f);
    float inv3 = 1.0f / sqrtf(var + EPS_);
    float r[3];
#pragma unroll
    for (int c = 0; c < 3; ++c) {
      float zz = (z[c] - mu3) * inv3 * gf[c] + betaf[c];
      r[c] = zz > 0.0f ? zz : 0.0f;
    }
#pragma unroll
    for (int c = 0; c < 3; ++c) {
      float sv = bf2[c];
#pragma unroll
      for (int i = 0; i < 3; ++i) sv = fmaf(r[i], Wf2[i * 3 + c], sv);
      out[b * 3 + c] = sv;
    }
  }
}

// ---------------------------------------------------------------------------
extern "C" void kernel_launch(void* const* d_in, const int* in_sizes, int n_in,
                              void* d_out, int out_size, void* d_ws, size_t ws_size,
                              hipStream_t stream) {
  const float* hs    = (const float*)d_in[0];
  const float* Wd    = (const float*)d_in[1];
  const float* bd    = (const float*)d_in[2];
  const float* Wo    = (const float*)d_in[3];
  const float* bo    = (const float*)d_in[4];
  const float* Wr    = (const float*)d_in[5];
  const float* br    = (const float*)d_in[6];
  const float* We1   = (const float*)d_in[7];
  const float* be1   = (const float*)d_in[8];
  const float* g1    = (const float*)d_in[9];
  const float* beta1 = (const float*)d_in[10];
  const float* We2   = (const float*)d_in[11];
  const float* be2   = (const float*)d_in[12];
  const float* Wp    = (const float*)d_in[13];
  const float* bp    = (const float*)d_in[14];
  const float* Wf1   = (const float*)d_in[15];
  const float* bf1   = (const float*)d_in[16];
  const float* gf    = (const float*)d_in[17];
  const float* betaf = (const float*)d_in[18];
  const float* Wf2   = (const float*)d_in[19];
  const float* bf2   = (const float*)d_in[20];
  float* out = (float*)d_out;

  char* w = (char*)d_ws;
  size_t off = 0;
  auto alloc = [&](size_t bytes) {
    void* p = w + off;
    off = (off + bytes + 255) & ~(size_t)255;
    return p;
  };
  ushort* m_hi   = (ushort*)alloc((size_t)B_ * H_ * 2);
  ushort* m_lo   = (ushort*)alloc((size_t)B_ * H_ * 2);
  ushort* cls_hi = (ushort*)alloc((size_t)B_ * H_ * 2);
  ushort* cls_lo = (ushort*)alloc((size_t)B_ * H_ * 2);
  ushort* wd_hi  = (ushort*)alloc((size_t)H_ * H_ * 2);
  ushort* wd_lo  = (ushort*)alloc((size_t)H_ * H_ * 2);
  ushort* we1_hi = (ushort*)alloc((size_t)E_ * H_ * HID_ * 2);
  ushort* we1_lo = (ushort*)alloc((size_t)E_ * H_ * HID_ * 2);
  float* ws_t    = (float*)alloc((size_t)B_ * H_ * 4);
  float* ws_h1   = (float*)alloc((size_t)B_ * K_ * HID_ * 4);
  float* ws_wc   = (float*)alloc((size_t)E_ * HID_ * 3 * 4);
  float* ws_bc   = (float*)alloc(E_ * 3 * 4);
  float* ws_prob = (float*)alloc(B_ * K_ * 4);
  int* ws_idx = (int*)alloc(B_ * K_ * 4);
  int* ws_cnt = (int*)alloc(E_ * 4);
  int* ws_pl  = (int*)alloc(E_ * B_ * 4);
  if (off > ws_size) return;

  hipMemsetAsync(ws_cnt, 0, E_ * sizeof(int), stream);

  prep_kernel<<<NB_PREP, 256, 0, stream>>>(hs, Wd, We1, We2, Wp, bp, Wr, br, be2,
                                           m_hi, m_lo, cls_hi, cls_lo, wd_hi, wd_lo,
                                           we1_hi, we1_lo, ws_wc, ws_bc,
                                           ws_idx, ws_prob, ws_cnt, ws_pl);
  gemm_mega<<<dim3(8, 8, 17), 256, 0, stream>>>(m_hi, m_lo, cls_hi, cls_lo,
                                                wd_hi, wd_lo, we1_hi, we1_lo,
                                                bd, be1, ws_cnt, ws_pl, ws_t, ws_h1);
  epi_kernel<<<B_, 256, 0, stream>>>(ws_t, Wo, bo, ws_h1, g1, beta1,
                                     ws_idx, ws_prob, ws_wc, ws_bc,
                                     Wf1, bf1, gf, betaf, Wf2, bf2, out);
}

// Round 5
// 308.520 us; speedup vs baseline: 2.2303x; 1.1450x over previous
//
#include <hip/hip_runtime.h>
#include <math.h>

#define B_ 1024
#define S_ 128
#define H_ 1024
#define E_ 16
#define HID_ 1024
#define K_ 4
#define C_ 3
#define EPS_ 1e-5f

// prep kernel segment offsets (block ranges)
#define NB_MEAN 1024
#define NB_WD 256
#define NB_WE1 4096
#define NB_WC 4096
#define NB_RT 256
#define NB_BC 4
#define OFF_WD (NB_MEAN)
#define OFF_WE1 (OFF_WD + NB_WD)
#define OFF_WC (OFF_WE1 + NB_WE1)
#define OFF_RT (OFF_WC + NB_WC)
#define OFF_BC (OFF_RT + NB_RT)
#define NB_PREP (OFF_BC + NB_BC)

typedef __attribute__((ext_vector_type(8))) __bf16 bf16x8;
typedef __attribute__((ext_vector_type(4))) float f32x4;

__device__ __forceinline__ ushort bf16_rn(float f) {
  unsigned u = __float_as_uint(f);
  u += 0x7FFF + ((u >> 16) & 1);
  return (ushort)(u >> 16);
}
__device__ __forceinline__ float bf16_to_f(ushort h) {
  return __uint_as_float(((unsigned)h) << 16);
}
__device__ __forceinline__ void split2(float f, ushort& h, ushort& l) {
  h = bf16_rn(f);
  l = bf16_rn(f - bf16_to_f(h));
}
__device__ __forceinline__ void gload_lds16(const void* g, void* l) {
  __builtin_amdgcn_global_load_lds((const __attribute__((address_space(1))) void*)g,
                                   (__attribute__((address_space(3))) void*)l, 16, 0, 0);
}
__device__ __forceinline__ void waveRed3(float& s0, float& s1, float& s2) {
#pragma unroll
  for (int off = 32; off; off >>= 1) {
    s0 += __shfl_down(s0, off); s1 += __shfl_down(s1, off); s2 += __shfl_down(s2, off);
  }
}

// ---------------------------------------------------------------------------
// Phase A: prep mega-kernel (unchanged). Independent segments by block range.
// ---------------------------------------------------------------------------
__global__ __launch_bounds__(256) void prep_kernel(
    const float* __restrict__ hs,
    const float* __restrict__ Wd, const float* __restrict__ We1,
    const float* __restrict__ We2, const float* __restrict__ Wp, const float* __restrict__ bp,
    const float* __restrict__ Wr, const float* __restrict__ br,
    const float* __restrict__ be2,
    ushort* __restrict__ m_hi, ushort* __restrict__ m_lo,
    ushort* __restrict__ cls_hi, ushort* __restrict__ cls_lo,
    ushort* __restrict__ wd_hi, ushort* __restrict__ wd_lo,
    ushort* __restrict__ we1_hi, ushort* __restrict__ we1_lo,
    float* __restrict__ Wcomb, float* __restrict__ bcomb,
    int* __restrict__ topk_idx, float* __restrict__ topk_prob,
    int* __restrict__ counts, int* __restrict__ pairlist) {
  __shared__ float tbuf[64][65];
  const int blk = blockIdx.x;
  const int tid = threadIdx.x;

  if (blk < NB_MEAN) {
    // ---- mean over S + cls row, emit hi/lo bf16 splits ----
    int gid = blk * 256 + tid;
    int b = gid >> 8;
    int h4 = (gid & 255) << 2;
    const float* p = hs + (size_t)b * S_ * H_ + h4;
    float4 v0 = *(const float4*)p;
    float sx = v0.x, sy = v0.y, sz = v0.z, sw = v0.w;
#pragma unroll 8
    for (int s = 1; s < S_; ++s) {
      float4 v = *(const float4*)(p + (size_t)s * H_);
      sx += v.x; sy += v.y; sz += v.z; sw += v.w;
    }
    const float inv = 1.0f / (float)S_;
    float mv[4] = {sx * inv, sy * inv, sz * inv, sw * inv};
    float cv[4] = {v0.x, v0.y, v0.z, v0.w};
    ushort4 mh, ml, ch, cl;
    split2(mv[0], mh.x, ml.x); split2(mv[1], mh.y, ml.y); split2(mv[2], mh.z, ml.z); split2(mv[3], mh.w, ml.w);
    split2(cv[0], ch.x, cl.x); split2(cv[1], ch.y, cl.y); split2(cv[2], ch.z, cl.z); split2(cv[3], ch.w, cl.w);
    size_t o = (size_t)b * H_ + h4;
    *(ushort4*)&m_hi[o] = mh; *(ushort4*)&m_lo[o] = ml;
    *(ushort4*)&cls_hi[o] = ch; *(ushort4*)&cls_lo[o] = cl;
  } else if (blk < OFF_WC) {
    // ---- weight transpose + hi/lo split (Wd or one We1 expert) ----
    int t, zmat;
    const float* in;
    ushort *oh, *ol;
    if (blk < OFF_WE1) { t = blk - OFF_WD; zmat = 0; in = Wd; oh = wd_hi; ol = wd_lo; }
    else { int t2 = blk - OFF_WE1; zmat = t2 >> 8; t = t2 & 255; in = We1; oh = we1_hi; ol = we1_lo; }
    const int k0 = (t & 15) * 64, n0 = (t >> 4) * 64;
    const size_t mbase = (size_t)zmat * (1024 * 1024);
    const int c4 = (tid & 15) << 2;
    const int r0 = tid >> 4;
#pragma unroll
    for (int p = 0; p < 4; ++p) {
      int row = r0 + p * 16;
      float4 v = *(const float4*)&in[mbase + (size_t)(k0 + row) * 1024 + n0 + c4];
      tbuf[row][c4] = v.x; tbuf[row][c4 + 1] = v.y; tbuf[row][c4 + 2] = v.z; tbuf[row][c4 + 3] = v.w;
    }
    __syncthreads();
    const int k4 = (tid & 15) << 2;
#pragma unroll
    for (int p = 0; p < 4; ++p) {
      int n = r0 + p * 16;
      ushort4 hh, ll;
      split2(tbuf[k4 + 0][n], hh.x, ll.x);
      split2(tbuf[k4 + 1][n], hh.y, ll.y);
      split2(tbuf[k4 + 2][n], hh.z, ll.z);
      split2(tbuf[k4 + 3][n], hh.w, ll.w);
      size_t o = mbase + (size_t)(n0 + n) * 1024 + k0 + k4;
      *(ushort4*)&oh[o] = hh;
      *(ushort4*)&ol[o] = ll;
    }
  } else if (blk < OFF_RT) {
    // ---- Wcomb[e*HID+d,:] = We2[e,d,:] @ Wp ----
    const int row = (blk - OFF_WC) * 4 + (tid >> 6);
    const int lane = tid & 63;
    const float* wr = We2 + (size_t)row * HID_;
    float s0 = 0, s1 = 0, s2 = 0;
    for (int f = lane; f < HID_; f += 64) {
      float v = wr[f];
      s0 = fmaf(v, Wp[f * 3 + 0], s0);
      s1 = fmaf(v, Wp[f * 3 + 1], s1);
      s2 = fmaf(v, Wp[f * 3 + 2], s2);
    }
    waveRed3(s0, s1, s2);
    if (lane == 0) {
      Wcomb[row * 3 + 0] = s0; Wcomb[row * 3 + 1] = s1; Wcomb[row * 3 + 2] = s2;
    }
  } else if (blk < OFF_BC) {
    // ---- router: one wave per sample, 4 samples per block ----
    const int lane = tid & 63;
    const int b = (blk - OFF_RT) * 4 + (tid >> 6);
    const float* cls = hs + (size_t)b * S_ * H_;
    const int e = lane & 15, part = lane >> 4;
    float sum = 0.0f;
    for (int i = part * 256; i < part * 256 + 256; ++i)
      sum = fmaf(cls[i], Wr[i * E_ + e], sum);
    sum += __shfl_down(sum, 32);
    sum += __shfl_down(sum, 16);
    float lg[E_];
#pragma unroll
    for (int i = 0; i < E_; ++i) lg[i] = __shfl(sum, i);
    if (lane == 0) {
      for (int i = 0; i < E_; ++i) lg[i] += br[i];
      int idx[K_]; float tv[K_];
      for (int k = 0; k < K_; ++k) {
        int bi = 0; float bv = -1e30f;
        for (int i = 0; i < E_; ++i) { if (lg[i] > bv) { bv = lg[i]; bi = i; } }
        idx[k] = bi; tv[k] = bv; lg[bi] = -1e30f;
      }
      float mx = tv[0], ssum = 0.0f, p[K_];
      for (int k = 0; k < K_; ++k) { p[k] = expf(tv[k] - mx); ssum += p[k]; }
      for (int k = 0; k < K_; ++k) {
        p[k] /= ssum;
        topk_idx[b * K_ + k] = idx[k];
        topk_prob[b * K_ + k] = p[k];
        int pos = atomicAdd(&counts[idx[k]], 1);
        pairlist[idx[k] * B_ + pos] = b * K_ + k;
      }
    }
  } else {
    // ---- bcomb[e,:] = be2[e,:] @ Wp + bp ----
    const int e = (blk - OFF_BC) * 4 + (tid >> 6);
    const int lane = tid & 63;
    const float* wr = be2 + (size_t)e * HID_;
    float s0 = 0, s1 = 0, s2 = 0;
    for (int f = lane; f < HID_; f += 64) {
      float v = wr[f];
      s0 = fmaf(v, Wp[f * 3 + 0], s0);
      s1 = fmaf(v, Wp[f * 3 + 1], s1);
      s2 = fmaf(v, Wp[f * 3 + 2], s2);
    }
    waveRed3(s0, s1, s2);
    if (lane == 0) {
      bcomb[e * 3 + 0] = s0 + bp[0]; bcomb[e * 3 + 1] = s1 + bp[1]; bcomb[e * 3 + 2] = s2 + bp[2];
    }
  }
}

// ---------------------------------------------------------------------------
// Phase B: unified MFMA GEMM with SPLIT-K=2 for occupancy. blockIdx.y encodes
// (m-tile, k-half): mt = y>>1, kh = y&1; each block sums K in [kh*512,+512)
// and writes a RAW partial (no bias/tanh — moved to epilogue, which sums the
// two halves; exact since tanh is the only nonlinearity and it's applied
// after the full sum). z<16: grouped expert GEMM -> h1part[kh].
// z==16: cls @ Wd -> tpart[kh]. 640 active blocks (vs 320) => ~2.5 blocks/CU,
// hides the vmcnt(0)+barrier drain that was fully exposed at 1.25 waves/SIMD.
// ---------------------------------------------------------------------------
__global__ __launch_bounds__(256) void gemm_mega(
    const ushort* __restrict__ m_hi, const ushort* __restrict__ m_lo,
    const ushort* __restrict__ cls_hi, const ushort* __restrict__ cls_lo,
    const ushort* __restrict__ wd_hi, const ushort* __restrict__ wd_lo,
    const ushort* __restrict__ we1_hi, const ushort* __restrict__ we1_lo,
    const int* __restrict__ counts, const int* __restrict__ pairlist,
    float* __restrict__ tA, float* __restrict__ tB,
    float* __restrict__ h1A, float* __restrict__ h1B) {
  __shared__ __align__(16) ushort ldsAh[4096], ldsAl[4096], ldsBh[4096], ldsBl[4096];
  const int z = blockIdx.z;
  const int tid = threadIdx.x;
  const int lane = tid & 63, w = tid >> 6;
  const int mt = blockIdx.y >> 1, kh = blockIdx.y & 1;
  const int m0 = mt * 128, n0 = blockIdx.x * 128;
  const int kbase = kh * 512;
  const ushort* srcp[8];
  ushort* ldst = (w == 0) ? ldsAh : (w == 1) ? ldsAl : (w == 2) ? ldsBh : ldsBl;
  int n_e;
  if (z == 16) {
    n_e = B_;
    const ushort* sbase = (w == 0) ? cls_hi : (w == 1) ? cls_lo : (w == 2) ? wd_hi : wd_lo;
    const int base0 = (w < 2) ? m0 : n0;
#pragma unroll
    for (int s = 0; s < 8; ++s) {
      int idx = base0 + s * 16 + (lane & 15);
      srcp[s] = sbase + (size_t)idx * H_ + ((lane >> 4) << 3);
    }
  } else {
    n_e = counts[z];
    if (m0 >= n_e) return;
    if (w < 2) {
      const ushort* sbase = (w == 0) ? m_hi : m_lo;
#pragma unroll
      for (int s = 0; s < 8; ++s) {
        int r = m0 + s * 16 + (lane & 15);
        if (r >= n_e) r = n_e - 1;
        int srow = pairlist[z * B_ + r] >> 2;
        srcp[s] = sbase + (size_t)srow * H_ + ((lane >> 4) << 3);
      }
    } else {
      const ushort* sbase = ((w == 2) ? we1_hi : we1_lo) + (size_t)z * H_ * HID_;
#pragma unroll
      for (int s = 0; s < 8; ++s) {
        int col = n0 + s * 16 + (lane & 15);
        srcp[s] = sbase + (size_t)col * H_ + ((lane >> 4) << 3);
      }
    }
  }
  const int wr = w >> 1, wc = w & 1;
  f32x4 acc[4][4] = {};
  for (int k0 = kbase; k0 < kbase + 512; k0 += 32) {
#pragma unroll
    for (int s = 0; s < 8; ++s)
      gload_lds16(srcp[s] + k0, ldst + s * 512);
    __syncthreads();
    bf16x8 ah[4], al[4], bh[4], bl[4];
#pragma unroll
    for (int i = 0; i < 4; ++i) {
      int off = (wr * 4 + i) * 512 + lane * 8;
      ah[i] = *(const bf16x8*)&ldsAh[off];
      al[i] = *(const bf16x8*)&ldsAl[off];
    }
#pragma unroll
    for (int j = 0; j < 4; ++j) {
      int off = (wc * 4 + j) * 512 + lane * 8;
      bh[j] = *(const bf16x8*)&ldsBh[off];
      bl[j] = *(const bf16x8*)&ldsBl[off];
    }
#pragma unroll
    for (int i = 0; i < 4; ++i)
#pragma unroll
      for (int j = 0; j < 4; ++j) {
        acc[i][j] = __builtin_amdgcn_mfma_f32_16x16x32_bf16(ah[i], bh[j], acc[i][j], 0, 0, 0);
        acc[i][j] = __builtin_amdgcn_mfma_f32_16x16x32_bf16(ah[i], bl[j], acc[i][j], 0, 0, 0);
        acc[i][j] = __builtin_amdgcn_mfma_f32_16x16x32_bf16(al[i], bh[j], acc[i][j], 0, 0, 0);
      }
    __syncthreads();
  }
  const int lr = (lane >> 4) << 2, lc = lane & 15;
  if (z == 16) {
    float* tp = kh ? tB : tA;
#pragma unroll
    for (int i = 0; i < 4; ++i) {
      int row = m0 + wr * 64 + i * 16 + lr;
#pragma unroll
      for (int j = 0; j < 4; ++j) {
        int col = n0 + wc * 64 + j * 16 + lc;
#pragma unroll
        for (int r = 0; r < 4; ++r)
          tp[(size_t)(row + r) * H_ + col] = acc[i][j][r];
      }
    }
  } else {
    float* hp = kh ? h1B : h1A;
#pragma unroll
    for (int i = 0; i < 4; ++i) {
      int pr[4]; bool ok[4];
#pragma unroll
      for (int r = 0; r < 4; ++r) {
        int li = m0 + wr * 64 + i * 16 + lr + r;
        ok[r] = li < n_e;
        pr[r] = pairlist[z * B_ + (ok[r] ? li : n_e - 1)];
      }
#pragma unroll
      for (int j = 0; j < 4; ++j) {
        int col = n0 + wc * 64 + j * 16 + lc;
#pragma unroll
        for (int r = 0; r < 4; ++r)
          if (ok[r]) hp[(size_t)pr[r] * HID_ + col] = acc[i][j][r];
      }
    }
  }
}

// ---------------------------------------------------------------------------
// Phase C: fused epilogue. One block per sample b (4 waves). Wave w handles
// pair b*4+w: sum split-K partials + be1 -> LN -> exact gelu -> dot Wcomb[e]
// * prob. Also per-wave 256-chunk of ologits with t = tanh(tA+tB+bd).
// Cross-wave combine in LDS (fixed order), thread 0 does the final head.
// ---------------------------------------------------------------------------
__global__ __launch_bounds__(256) void epi_kernel(
    const float* __restrict__ tA, const float* __restrict__ tB,
    const float* __restrict__ bd,
    const float* __restrict__ Wo, const float* __restrict__ bo,
    const float* __restrict__ h1A, const float* __restrict__ h1B,
    const float* __restrict__ be1,
    const float* __restrict__ g1, const float* __restrict__ beta1,
    const int* __restrict__ topk_idx, const float* __restrict__ topk_prob,
    const float* __restrict__ Wcomb, const float* __restrict__ bcomb,
    const float* __restrict__ Wf1, const float* __restrict__ bf1,
    const float* __restrict__ gf, const float* __restrict__ betaf,
    const float* __restrict__ Wf2, const float* __restrict__ bf2,
    float* __restrict__ out) {
  const int b = blockIdx.x;
  const int tid = threadIdx.x;
  const int w = tid >> 6, lane = tid & 63;
  __shared__ float sCtr[4][3];
  __shared__ float sOl[4][3];

  // ---- per-wave: expert pair LN + gelu + Wcomb dot ----
  const int pair = b * K_ + w;
  const int e = topk_idx[pair];
  const float prob = topk_prob[pair];
  const float* hrA = h1A + (size_t)pair * HID_;
  const float* hrB = h1B + (size_t)pair * HID_;
  const float* ber = be1 + (size_t)e * HID_;
  float4 x[4];
#pragma unroll
  for (int q = 0; q < 4; ++q) {
    const int d = q * 256 + lane * 4;
    float4 a = *(const float4*)&hrA[d];
    float4 bq = *(const float4*)&hrB[d];
    float4 be = *(const float4*)&ber[d];
    x[q].x = a.x + bq.x + be.x; x[q].y = a.y + bq.y + be.y;
    x[q].z = a.z + bq.z + be.z; x[q].w = a.w + bq.w + be.w;
  }
  float s = 0;
#pragma unroll
  for (int q = 0; q < 4; ++q) s += x[q].x + x[q].y + x[q].z + x[q].w;
#pragma unroll
  for (int off = 32; off; off >>= 1) s += __shfl_down(s, off);
  const float mu = __shfl(s, 0) * (1.0f / HID_);
  float sq = 0;
#pragma unroll
  for (int q = 0; q < 4; ++q) {
    float dx = x[q].x - mu, dy = x[q].y - mu, dz = x[q].z - mu, dw = x[q].w - mu;
    sq += dx * dx + dy * dy + dz * dz + dw * dw;
  }
#pragma unroll
  for (int off = 32; off; off >>= 1) sq += __shfl_down(sq, off);
  const float inv = 1.0f / sqrtf(__shfl(sq, 0) * (1.0f / HID_) + EPS_);
  float c0 = 0, c1 = 0, c2 = 0;
#pragma unroll
  for (int q = 0; q < 4; ++q) {
    const int d = q * 256 + lane * 4;
    float4 gg = *(const float4*)&g1[(size_t)e * HID_ + d];
    float4 bb = *(const float4*)&beta1[(size_t)e * HID_ + d];
    float xv[4] = {x[q].x, x[q].y, x[q].z, x[q].w};
    float gv[4] = {gg.x, gg.y, gg.z, gg.w};
    float bv[4] = {bb.x, bb.y, bb.z, bb.w};
#pragma unroll
    for (int i = 0; i < 4; ++i) {
      float v = (xv[i] - mu) * inv * gv[i] + bv[i];
      v = 0.5f * v * (1.0f + erff(v * 0.70710678118654752440f));  // exact gelu
      const float* wc = &Wcomb[(size_t)(e * HID_ + d + i) * 3];
      c0 = fmaf(v, wc[0], c0); c1 = fmaf(v, wc[1], c1); c2 = fmaf(v, wc[2], c2);
    }
  }
  waveRed3(c0, c1, c2);
  if (lane == 0) {
    sCtr[w][0] = prob * (c0 + bcomb[e * 3 + 0]);
    sCtr[w][1] = prob * (c1 + bcomb[e * 3 + 1]);
    sCtr[w][2] = prob * (c2 + bcomb[e * 3 + 2]);
  }

  // ---- per-wave: 256-chunk partial of ologits (tanh applied here) ----
  {
    const int h0 = w * 256 + lane * 4;
    float4 ta = *(const float4*)&tA[(size_t)b * H_ + h0];
    float4 tb = *(const float4*)&tB[(size_t)b * H_ + h0];
    float4 bdv = *(const float4*)&bd[h0];
    float tvv[4] = {tanhf(ta.x + tb.x + bdv.x), tanhf(ta.y + tb.y + bdv.y),
                    tanhf(ta.z + tb.z + bdv.z), tanhf(ta.w + tb.w + bdv.w)};
    float o0 = 0, o1 = 0, o2 = 0;
#pragma unroll
    for (int i = 0; i < 4; ++i) {
      const float* wo = &Wo[(size_t)(h0 + i) * 3];
      o0 = fmaf(tvv[i], wo[0], o0); o1 = fmaf(tvv[i], wo[1], o1); o2 = fmaf(tvv[i], wo[2], o2);
    }
    waveRed3(o0, o1, o2);
    if (lane == 0) { sOl[w][0] = o0; sOl[w][1] = o1; sOl[w][2] = o2; }
  }
  __syncthreads();

  // ---- thread 0: combine + final head ----
  if (tid == 0) {
    float comb[6];
#pragma unroll
    for (int c = 0; c < 3; ++c) {
      comb[c] = sOl[0][c] + sOl[1][c] + sOl[2][c] + sOl[3][c] + bo[c];
      comb[3 + c] = sCtr[0][c] + sCtr[1][c] + sCtr[2][c] + sCtr[3][c];
    }
    float z[3];
#pragma unroll
    for (int c = 0; c < 3; ++c) {
      float sv = bf1[c];
#pragma unroll
      for (int i = 0; i < 6; ++i) sv = fmaf(comb[i], Wf1[i * 3 + c], sv);
      z[c] = sv;
    }
    float mu3 = (z[0] + z[1] + z[2]) * (1.0f / 3.0f);
    float v0 = z[0] - mu3, v1 = z[1] - mu3, v2 = z[2] - mu3;
    float var = (v0 * v0 + v1 * v1 + v2 * v2) * (1.0f / 3.0f);
    float inv3 = 1.0f / sqrtf(var + EPS_);
    float r[3];
#pragma unroll
    for (int c = 0; c < 3; ++c) {
      float zz = (z[c] - mu3) * inv3 * gf[c] + betaf[c];
      r[c] = zz > 0.0f ? zz : 0.0f;
    }
#pragma unroll
    for (int c = 0; c < 3; ++c) {
      float sv = bf2[c];
#pragma unroll
      for (int i = 0; i < 3; ++i) sv = fmaf(r[i], Wf2[i * 3 + c], sv);
      out[b * 3 + c] = sv;
    }
  }
}

// ---------------------------------------------------------------------------
extern "C" void kernel_launch(void* const* d_in, const int* in_sizes, int n_in,
                              void* d_out, int out_size, void* d_ws, size_t ws_size,
                              hipStream_t stream) {
  const float* hs    = (const float*)d_in[0];
  const float* Wd    = (const float*)d_in[1];
  const float* bd    = (const float*)d_in[2];
  const float* Wo    = (const float*)d_in[3];
  const float* bo    = (const float*)d_in[4];
  const float* Wr    = (const float*)d_in[5];
  const float* br    = (const float*)d_in[6];
  const float* We1   = (const float*)d_in[7];
  const float* be1   = (const float*)d_in[8];
  const float* g1    = (const float*)d_in[9];
  const float* beta1 = (const float*)d_in[10];
  const float* We2   = (const float*)d_in[11];
  const float* be2   = (const float*)d_in[12];
  const float* Wp    = (const float*)d_in[13];
  const float* bp    = (const float*)d_in[14];
  const float* Wf1   = (const float*)d_in[15];
  const float* bf1   = (const float*)d_in[16];
  const float* gf    = (const float*)d_in[17];
  const float* betaf = (const float*)d_in[18];
  const float* Wf2   = (const float*)d_in[19];
  const float* bf2   = (const float*)d_in[20];
  float* out = (float*)d_out;

  char* w = (char*)d_ws;
  size_t off = 0;
  auto alloc = [&](size_t bytes) {
    void* p = w + off;
    off = (off + bytes + 255) & ~(size_t)255;
    return p;
  };
  ushort* m_hi   = (ushort*)alloc((size_t)B_ * H_ * 2);
  ushort* m_lo   = (ushort*)alloc((size_t)B_ * H_ * 2);
  ushort* cls_hi = (ushort*)alloc((size_t)B_ * H_ * 2);
  ushort* cls_lo = (ushort*)alloc((size_t)B_ * H_ * 2);
  ushort* wd_hi  = (ushort*)alloc((size_t)H_ * H_ * 2);
  ushort* wd_lo  = (ushort*)alloc((size_t)H_ * H_ * 2);
  ushort* we1_hi = (ushort*)alloc((size_t)E_ * H_ * HID_ * 2);
  ushort* we1_lo = (ushort*)alloc((size_t)E_ * H_ * HID_ * 2);
  float* ws_tA   = (float*)alloc((size_t)B_ * H_ * 4);
  float* ws_tB   = (float*)alloc((size_t)B_ * H_ * 4);
  float* ws_h1A  = (float*)alloc((size_t)B_ * K_ * HID_ * 4);
  float* ws_h1B  = (float*)alloc((size_t)B_ * K_ * HID_ * 4);
  float* ws_wc   = (float*)alloc((size_t)E_ * HID_ * 3 * 4);
  float* ws_bc   = (float*)alloc(E_ * 3 * 4);
  float* ws_prob = (float*)alloc(B_ * K_ * 4);
  int* ws_idx = (int*)alloc(B_ * K_ * 4);
  int* ws_cnt = (int*)alloc(E_ * 4);
  int* ws_pl  = (int*)alloc(E_ * B_ * 4);
  if (off > ws_size) return;

  hipMemsetAsync(ws_cnt, 0, E_ * sizeof(int), stream);

  prep_kernel<<<NB_PREP, 256, 0, stream>>>(hs, Wd, We1, We2, Wp, bp, Wr, br, be2,
                                           m_hi, m_lo, cls_hi, cls_lo, wd_hi, wd_lo,
                                           we1_hi, we1_lo, ws_wc, ws_bc,
                                           ws_idx, ws_prob, ws_cnt, ws_pl);
  gemm_mega<<<dim3(8, 16, 17), 256, 0, stream>>>(m_hi, m_lo, cls_hi, cls_lo,
                                                 wd_hi, wd_lo, we1_hi, we1_lo,
                                                 ws_cnt, ws_pl, ws_tA, ws_tB, ws_h1A, ws_h1B);
  epi_kernel<<<B_, 256, 0, stream>>>(ws_tA, ws_tB, bd, Wo, bo, ws_h1A, ws_h1B, be1,
                                     g1, beta1, ws_idx, ws_prob, ws_wc, ws_bc,
                                     Wf1, bf1, gf, betaf, Wf2, bf2, out);
}